// Round 2
// baseline (1197.659 us; speedup 1.0000x reference)
//
#include <hip/hip_runtime.h>
#include <cstdint>
#include <cstddef>

#define N_NODES 50000
#define N_EDGES 600000
#define NLAYER  4
#define NGRAPH  64

// ---------- CSR build ----------
__global__ void count_deg(const int* __restrict__ dst, int* __restrict__ deg) {
    int e = blockIdx.x * 256 + threadIdx.x;
    if (e < N_EDGES) atomicAdd(&deg[dst[e]], 1);
}

__global__ void scan_deg(const int* __restrict__ deg, int* __restrict__ rowp) {
    __shared__ int sd[1024];
    __shared__ int carry_s;
    int tid = threadIdx.x;
    if (tid == 0) { carry_s = 0; rowp[0] = 0; }
    __syncthreads();
    for (int base = 0; base < N_NODES; base += 1024) {
        int i = base + tid;
        int v = (i < N_NODES) ? deg[i] : 0;
        sd[tid] = v; __syncthreads();
        for (int off = 1; off < 1024; off <<= 1) {
            int t = (tid >= off) ? sd[tid - off] : 0;
            __syncthreads();
            sd[tid] += t; __syncthreads();
        }
        int c = carry_s;
        if (i < N_NODES) rowp[i + 1] = c + sd[tid];
        __syncthreads();
        if (tid == 0) carry_s = c + sd[1023];
        __syncthreads();
    }
}

__global__ void fill_csr(const int* __restrict__ src, const int* __restrict__ dst,
                         const int* __restrict__ rowp, int* __restrict__ cursor,
                         int* __restrict__ col) {
    int e = blockIdx.x * 256 + threadIdx.x;
    if (e < N_EDGES) {
        int d = dst[e];
        int pos = atomicAdd(&cursor[d], 1);
        col[rowp[d] + pos] = src[e];
    }
}

// ---------- GIN aggregation: agg[i] = (1+eps)*x[i] + sum_{j in N(i)} x[j] ----------
// one wave (64 lanes) per node; lane handles 2 contiguous floats (float2)
__global__ __launch_bounds__(256) void agg_kernel(
    const float2* __restrict__ xin, const int* __restrict__ rowp,
    const int* __restrict__ col, const float* __restrict__ eps_all, int layer,
    float2* __restrict__ agg) {
    int node = blockIdx.x * 4 + (threadIdx.x >> 6);
    int lane = threadIdx.x & 63;
    if (node >= N_NODES) return;
    float ep = 1.0f + eps_all[layer];
    float2 v = xin[(size_t)node * 64 + lane];
    float a0 = ep * v.x, a1 = ep * v.y;
    int k0 = rowp[node], k1 = rowp[node + 1];
    for (int k = k0; k < k1; ++k) {
        int s = col[k];
        float2 u = xin[(size_t)s * 64 + lane];
        a0 += u.x; a1 += u.y;
    }
    agg[(size_t)node * 64 + lane] = make_float2(a0, a1);
}

// ---------- SGEMM: C[M,128] = relu(A[M,128] @ W[128,128] + bias), fp32 ----------
template <bool RELU>
__global__ __launch_bounds__(256) void gemm_f32(
    const float* __restrict__ A, const float* __restrict__ W,
    const float* __restrict__ bias, float* __restrict__ C, int M) {
    __shared__ float As[32][65];  // [k][m]
    __shared__ float Bs[32][65];  // [k][n]
    int tid = threadIdx.x;
    int bm = blockIdx.x * 64;
    int bn = blockIdx.y * 64;
    int tx = tid & 15, ty = tid >> 4;
    float acc[4][4] = {};
    for (int kb = 0; kb < 128; kb += 32) {
        {   // A tile: 64 rows x 32 k (8 float4 per row)
            int cu = tid & 7;    // float4 index within the 32-k slab
            int r0 = tid >> 3;   // 0..31
#pragma unroll
            for (int p = 0; p < 2; p++) {
                int r = r0 + p * 32;
                int row = bm + r;
                float4 v = (row < M)
                    ? ((const float4*)(A + (size_t)row * 128 + kb))[cu]
                    : make_float4(0.f, 0.f, 0.f, 0.f);
                As[4 * cu + 0][r] = v.x; As[4 * cu + 1][r] = v.y;
                As[4 * cu + 2][r] = v.z; As[4 * cu + 3][r] = v.w;
            }
        }
        {   // W tile: 32 k x 64 cols (16 float4 per k-row)
            int cu = tid & 15;   // float4 col index
            int k0 = tid >> 4;   // 0..15
#pragma unroll
            for (int p = 0; p < 2; p++) {
                int k = k0 + p * 16;
                float4 v = ((const float4*)(W + (size_t)(kb + k) * 128 + bn))[cu];
                Bs[k][4 * cu + 0] = v.x; Bs[k][4 * cu + 1] = v.y;
                Bs[k][4 * cu + 2] = v.z; Bs[k][4 * cu + 3] = v.w;
            }
        }
        __syncthreads();
#pragma unroll
        for (int k = 0; k < 32; k++) {
            float a[4], b[4];
#pragma unroll
            for (int i = 0; i < 4; i++) a[i] = As[k][ty * 4 + i];
#pragma unroll
            for (int j = 0; j < 4; j++) b[j] = Bs[k][tx * 4 + j];
#pragma unroll
            for (int i = 0; i < 4; i++)
#pragma unroll
                for (int j = 0; j < 4; j++) acc[i][j] += a[i] * b[j];
        }
        __syncthreads();
    }
    float4 bv = ((const float4*)(bias + bn))[tx];
#pragma unroll
    for (int i = 0; i < 4; i++) {
        int row = bm + ty * 4 + i;
        if (row >= M) continue;
        float4 o;
        o.x = acc[i][0] + bv.x; o.y = acc[i][1] + bv.y;
        o.z = acc[i][2] + bv.z; o.w = acc[i][3] + bv.w;
        if (RELU) {
            o.x = fmaxf(o.x, 0.f); o.y = fmaxf(o.y, 0.f);
            o.z = fmaxf(o.z, 0.f); o.w = fmaxf(o.w, 0.f);
        }
        ((float4*)(C + (size_t)row * 128 + bn))[tx] = o;
    }
}

// ---------- BN batch stats: per-column sum / sumsq over N rows ----------
__global__ __launch_bounds__(256) void bn_stats(const float* __restrict__ h2,
                                                float* __restrict__ sums) {
    int tid = threadIdx.x;
    int c = tid & 127;
    int rh = tid >> 7;  // 0..1
    float s = 0.f, s2 = 0.f;
    for (int r = blockIdx.x * 2 + rh; r < N_NODES; r += gridDim.x * 2) {
        float v = h2[(size_t)r * 128 + c];
        s += v; s2 += v * v;
    }
    __shared__ float l1[256], l2[256];
    l1[tid] = s; l2[tid] = s2; __syncthreads();
    if (tid < 128) {
        atomicAdd(&sums[c],       l1[tid] + l1[tid + 128]);
        atomicAdd(&sums[128 + c], l2[tid] + l2[tid + 128]);
    }
}

__global__ void bn_finalize(const float* __restrict__ sums,
                            const float* __restrict__ gamma, const float* __restrict__ beta,
                            int layer, float* __restrict__ coef) {
    int c = threadIdx.x;  // 128 threads
    float mean = sums[c] / (float)N_NODES;
    float var  = sums[128 + c] / (float)N_NODES - mean * mean;
    float istd = rsqrtf(var + 1e-5f);
    float a = istd * gamma[layer * 128 + c];
    coef[c]       = a;
    coef[128 + c] = beta[layer * 128 + c] - mean * a;
}

// ---------- normalize + fused per-graph pooled-sum accumulation (batch sorted) ----------
__global__ __launch_bounds__(128) void norm_pool(
    const float* __restrict__ h2, const float* __restrict__ coef,
    const int* __restrict__ batch, int layer,
    float* __restrict__ xout, float* __restrict__ pooled) {
    int c = threadIdx.x;
    int r0 = blockIdx.x * 64;
    int r1 = min(r0 + 64, N_NODES);
    float a = coef[c], d = coef[128 + c];
    float ps = 0.f;
    int curg = batch[r0];
    for (int r = r0; r < r1; ++r) {
        int g = batch[r];
        if (g != curg) {
            atomicAdd(&pooled[curg * 512 + layer * 128 + c], ps);
            ps = 0.f; curg = g;
        }
        float v = h2[(size_t)r * 128 + c] * a + d;
        xout[(size_t)r * 128 + c] = v;
        ps += v;
    }
    atomicAdd(&pooled[curg * 512 + layer * 128 + c], ps);
}

// ---------- head: one block per graph ----------
__global__ __launch_bounds__(256) void head_kernel(
    const float* __restrict__ pooled, const int* __restrict__ batch,
    const float* __restrict__ emb,
    const float* __restrict__ l1w, const float* __restrict__ l1b,
    const float* __restrict__ l2w, const float* __restrict__ l2b,
    const float* __restrict__ l4w, const float* __restrict__ l4b,
    float* __restrict__ out) {
    __shared__ float z[576];
    __shared__ float z1[256];
    __shared__ float z2[128];
    __shared__ float z3s[10];
    __shared__ float inv_cnt;
    int g = blockIdx.x;
    int tid = threadIdx.x;
    if (tid == 0) {
        int lo = 0, hi = N_NODES;
        while (lo < hi) { int m = (lo + hi) >> 1; if (batch[m] < g) lo = m + 1; else hi = m; }
        int s = lo;
        lo = 0; hi = N_NODES;
        while (lo < hi) { int m = (lo + hi) >> 1; if (batch[m] < g + 1) lo = m + 1; else hi = m; }
        inv_cnt = 1.0f / fmaxf((float)(lo - s), 1.0f);
    }
    __syncthreads();
    for (int j = tid; j < 512; j += 256) z[j] = pooled[g * 512 + j] * inv_cnt;
    if (tid < 64) z[512 + tid] = emb[g * 64 + tid];
    __syncthreads();
    {   // z1[256] = relu(z[576] @ l1w + b)
        float acc = l1b[tid];
        for (int j = 0; j < 576; j++) acc += z[j] * l1w[j * 256 + tid];
        z1[tid] = fmaxf(acc, 0.f);
    }
    __syncthreads();
    if (tid < 128) {
        float acc = l2b[tid];
        for (int j = 0; j < 256; j++) acc += z1[j] * l2w[j * 128 + tid];
        z2[tid] = fmaxf(acc, 0.f);
    }
    __syncthreads();
    if (tid < 10) {
        float acc = l4b[tid];
        for (int j = 0; j < 128; j++) acc += z2[j] * l4w[j * 10 + tid];
        z3s[tid] = acc;
    }
    __syncthreads();
    if (tid == 0) {
        float m = z3s[0];
        for (int i = 1; i < 10; i++) m = fmaxf(m, z3s[i]);
        float se = 0.f;
        for (int i = 0; i < 10; i++) se += expf(z3s[i] - m);
        float lse = m + logf(se);
        for (int i = 0; i < 10; i++) out[g * 10 + i] = z3s[i] - lse;
    }
}

extern "C" void kernel_launch(void* const* d_in, const int* in_sizes, int n_in,
                              void* d_out, int out_size, void* d_ws, size_t ws_size,
                              hipStream_t stream) {
    (void)in_sizes; (void)n_in; (void)out_size; (void)ws_size;
    const float* x0   = (const float*)d_in[0];    // x [N,128] fp32
    const int* ei     = (const int*)d_in[1];      // edge_index [2,E] (int32 on device)
    const int* src    = ei;
    const int* dst    = ei + N_EDGES;
    const int* batch  = (const int*)d_in[2];      // [N]
    const float* emb  = (const float*)d_in[3];    // [G,64]
    const float* eps  = (const float*)d_in[4];    // [L]
    const float* W1   = (const float*)d_in[5];    // [L,128,128]
    const float* b1   = (const float*)d_in[6];    // [L,128]
    const float* W2   = (const float*)d_in[7];
    const float* b2   = (const float*)d_in[8];
    const float* gamma= (const float*)d_in[9];
    const float* beta = (const float*)d_in[10];
    const float* l1w  = (const float*)d_in[11];   // [576,256]
    const float* l1b  = (const float*)d_in[12];
    const float* l2w  = (const float*)d_in[13];   // [256,128]
    const float* l2b  = (const float*)d_in[14];
    const float* l4w  = (const float*)d_in[15];   // [128,10]
    const float* l4b  = (const float*)d_in[16];

    char* ws = (char*)d_ws;
    size_t off = 0;
    auto alloc = [&](size_t bytes) -> char* {
        char* p = ws + off; off += (bytes + 255) & ~(size_t)255; return p;
    };
    int* rowp   = (int*)alloc((N_NODES + 1) * 4);
    int* deg    = (int*)alloc(N_NODES * 4);
    int* cursor = (int*)alloc(N_NODES * 4);
    int* col    = (int*)alloc(N_EDGES * 4);
    float* agg  = (float*)alloc((size_t)N_NODES * 128 * 4);  // also reused as h2
    float* h1   = (float*)alloc((size_t)N_NODES * 128 * 4);
    float* xa   = (float*)alloc((size_t)N_NODES * 128 * 4);
    float* xb   = (float*)alloc((size_t)N_NODES * 128 * 4);
    float* sums   = (float*)alloc(256 * 4);
    float* coef   = (float*)alloc(256 * 4);
    float* pooled = (float*)alloc(NGRAPH * 512 * 4);

    hipMemsetAsync(deg, 0, N_NODES * 4, stream);
    hipMemsetAsync(cursor, 0, N_NODES * 4, stream);
    hipMemsetAsync(pooled, 0, NGRAPH * 512 * 4, stream);

    count_deg<<<(N_EDGES + 255) / 256, 256, 0, stream>>>(dst, deg);
    scan_deg<<<1, 1024, 0, stream>>>(deg, rowp);
    fill_csr<<<(N_EDGES + 255) / 256, 256, 0, stream>>>(src, dst, rowp, cursor, col);

    const float* xin = x0;
    float* xout = xa;
    for (int l = 0; l < NLAYER; ++l) {
        agg_kernel<<<(N_NODES + 3) / 4, 256, 0, stream>>>(
            (const float2*)xin, rowp, col, eps, l, (float2*)agg);
        dim3 gg((N_NODES + 63) / 64, 2);
        float* h2 = agg;  // gemm2 overwrites agg in place (reads h1 only)
        gemm_f32<true><<<gg, 256, 0, stream>>>(agg, W1 + (size_t)l * 128 * 128,
                                               b1 + l * 128, h1, N_NODES);
        gemm_f32<true><<<gg, 256, 0, stream>>>(h1, W2 + (size_t)l * 128 * 128,
                                               b2 + l * 128, h2, N_NODES);
        hipMemsetAsync(sums, 0, 256 * 4, stream);
        bn_stats<<<128, 256, 0, stream>>>(h2, sums);
        bn_finalize<<<1, 128, 0, stream>>>(sums, gamma, beta, l, coef);
        norm_pool<<<(N_NODES + 63) / 64, 128, 0, stream>>>(h2, coef, batch, l,
                                                           xout, pooled);
        xin = xout;
        xout = (xout == xa) ? xb : xa;
    }
    head_kernel<<<NGRAPH, 256, 0, stream>>>(pooled, batch, emb, l1w, l1b, l2w, l2b,
                                            l4w, l4b, (float*)d_out);
}

// Round 3
// 952.492 us; speedup vs baseline: 1.2574x; 1.2574x over previous
//
#include <hip/hip_runtime.h>
#include <cstdint>
#include <cstddef>

#define N_NODES 50000
#define N_EDGES 600000
#define NLAYER  4
#define NGRAPH  64
#define SCAN_NB 196   // ceil(50000/256)

// ---------- CSR build ----------
__global__ void count_deg(const int* __restrict__ dst, int* __restrict__ deg) {
    int e = blockIdx.x * 256 + threadIdx.x;
    if (e < N_EDGES) atomicAdd(&deg[dst[e]], 1);
}

// block-local inclusive scan of deg -> bscan, block totals -> bsum
__global__ __launch_bounds__(256) void scan_l1(const int* __restrict__ deg,
                                               int* __restrict__ bscan,
                                               int* __restrict__ bsum) {
    __shared__ int sd[256];
    int tid = threadIdx.x;
    int i = blockIdx.x * 256 + tid;
    int v = (i < N_NODES) ? deg[i] : 0;
    sd[tid] = v; __syncthreads();
#pragma unroll
    for (int off = 1; off < 256; off <<= 1) {
        int t = (tid >= off) ? sd[tid - off] : 0;
        __syncthreads();
        sd[tid] += t; __syncthreads();
    }
    if (i < N_NODES) bscan[i] = sd[tid];
    if (tid == 255) bsum[blockIdx.x] = sd[255];
}

// exclusive scan of the 196 block totals
__global__ __launch_bounds__(256) void scan_l2(const int* __restrict__ bsum,
                                               int* __restrict__ boff) {
    __shared__ int sd[256];
    int tid = threadIdx.x;
    int v = (tid < SCAN_NB) ? bsum[tid] : 0;
    sd[tid] = v; __syncthreads();
#pragma unroll
    for (int off = 1; off < 256; off <<= 1) {
        int t = (tid >= off) ? sd[tid - off] : 0;
        __syncthreads();
        sd[tid] += t; __syncthreads();
    }
    if (tid < SCAN_NB) boff[tid] = sd[tid] - v;   // exclusive
}

__global__ __launch_bounds__(256) void scan_l3(const int* __restrict__ bscan,
                                               const int* __restrict__ boff,
                                               int* __restrict__ rowp) {
    int i = blockIdx.x * 256 + threadIdx.x;
    if (i == 0) rowp[0] = 0;
    if (i < N_NODES) rowp[i + 1] = bscan[i] + boff[blockIdx.x];
}

__global__ void fill_csr(const int* __restrict__ src, const int* __restrict__ dst,
                         const int* __restrict__ rowp, int* __restrict__ cursor,
                         int* __restrict__ col) {
    int e = blockIdx.x * 256 + threadIdx.x;
    if (e < N_EDGES) {
        int d = dst[e];
        int pos = atomicAdd(&cursor[d], 1);
        col[rowp[d] + pos] = src[e];
    }
}

// ---------- GIN aggregation with analytic BN of the previous layer ----------
// agg[i] = (1+eps) * norm(x_i) + sum_j norm(x_j)
//        = (1+eps) * (a*x_i+d) + a * sum_j x_j + deg_i * d
// one wave per node; lane handles 2 contiguous floats
__global__ __launch_bounds__(256) void agg_kernel(
    const float2* __restrict__ xin, const float* __restrict__ coef,  // nullable
    const int* __restrict__ rowp, const int* __restrict__ col,
    const float* __restrict__ eps_all, int layer,
    float2* __restrict__ agg) {
    int node = blockIdx.x * 4 + (threadIdx.x >> 6);
    int lane = threadIdx.x & 63;
    if (node >= N_NODES) return;
    float a0 = 1.f, a1 = 1.f, d0 = 0.f, d1 = 0.f;
    if (coef) {
        a0 = coef[2 * lane];       a1 = coef[2 * lane + 1];
        d0 = coef[128 + 2 * lane]; d1 = coef[128 + 2 * lane + 1];
    }
    float ep = 1.0f + eps_all[layer];
    float2 v = xin[(size_t)node * 64 + lane];
    int k0 = rowp[node], k1 = rowp[node + 1];
    float s0 = 0.f, s1 = 0.f;
    for (int k = k0; k < k1; ++k) {
        int s = col[k];
        float2 u = xin[(size_t)s * 64 + lane];
        s0 += u.x; s1 += u.y;
    }
    float deg = (float)(k1 - k0);
    float r0 = ep * (a0 * v.x + d0) + a0 * s0 + deg * d0;
    float r1 = ep * (a1 * v.y + d1) + a1 * s1 + deg * d1;
    agg[(size_t)node * 64 + lane] = make_float2(r0, r1);
}

// ---------- SGEMM: C[M,128] = relu(A[M,128] @ W[128,128] + bias), fp32 ----------
template <bool RELU>
__global__ __launch_bounds__(256) void gemm_f32(
    const float* __restrict__ A, const float* __restrict__ W,
    const float* __restrict__ bias, float* __restrict__ C, int M) {
    __shared__ float As[32][65];  // [k][m]
    __shared__ float Bs[32][65];  // [k][n]
    int tid = threadIdx.x;
    int bm = blockIdx.x * 64;
    int bn = blockIdx.y * 64;
    int tx = tid & 15, ty = tid >> 4;
    float acc[4][4] = {};
    for (int kb = 0; kb < 128; kb += 32) {
        {   // A tile: 64 rows x 32 k (8 float4 per row)
            int cu = tid & 7;
            int r0 = tid >> 3;
#pragma unroll
            for (int p = 0; p < 2; p++) {
                int r = r0 + p * 32;
                int row = bm + r;
                float4 v = (row < M)
                    ? ((const float4*)(A + (size_t)row * 128 + kb))[cu]
                    : make_float4(0.f, 0.f, 0.f, 0.f);
                As[4 * cu + 0][r] = v.x; As[4 * cu + 1][r] = v.y;
                As[4 * cu + 2][r] = v.z; As[4 * cu + 3][r] = v.w;
            }
        }
        {   // W tile: 32 k x 64 cols
            int cu = tid & 15;
            int k0 = tid >> 4;
#pragma unroll
            for (int p = 0; p < 2; p++) {
                int k = k0 + p * 16;
                float4 v = ((const float4*)(W + (size_t)(kb + k) * 128 + bn))[cu];
                Bs[k][4 * cu + 0] = v.x; Bs[k][4 * cu + 1] = v.y;
                Bs[k][4 * cu + 2] = v.z; Bs[k][4 * cu + 3] = v.w;
            }
        }
        __syncthreads();
#pragma unroll
        for (int k = 0; k < 32; k++) {
            float a[4], b[4];
#pragma unroll
            for (int i = 0; i < 4; i++) a[i] = As[k][ty * 4 + i];
#pragma unroll
            for (int j = 0; j < 4; j++) b[j] = Bs[k][tx * 4 + j];
#pragma unroll
            for (int i = 0; i < 4; i++)
#pragma unroll
                for (int j = 0; j < 4; j++) acc[i][j] += a[i] * b[j];
        }
        __syncthreads();
    }
    float4 bv = ((const float4*)(bias + bn))[tx];
#pragma unroll
    for (int i = 0; i < 4; i++) {
        int row = bm + ty * 4 + i;
        if (row >= M) continue;
        float4 o;
        o.x = acc[i][0] + bv.x; o.y = acc[i][1] + bv.y;
        o.z = acc[i][2] + bv.z; o.w = acc[i][3] + bv.w;
        if (RELU) {
            o.x = fmaxf(o.x, 0.f); o.y = fmaxf(o.y, 0.f);
            o.z = fmaxf(o.z, 0.f); o.w = fmaxf(o.w, 0.f);
        }
        ((float4*)(C + (size_t)row * 128 + bn))[tx] = o;
    }
}

// ---------- fused: per-column sum/sumsq + per-graph raw column sums (batch sorted) ----------
__global__ __launch_bounds__(128) void stats_pool(
    const float* __restrict__ h2, const int* __restrict__ batch,
    float* __restrict__ sums /*[256]*/, float* __restrict__ gsum /*[G*128]*/) {
    int c = threadIdx.x;
    int r0 = blockIdx.x * 64;
    int r1 = min(r0 + 64, N_NODES);
    float s = 0.f, s2 = 0.f, ps = 0.f;
    int curg = batch[r0];
    for (int r = r0; r < r1; ++r) {
        int g = batch[r];
        if (g != curg) {
            atomicAdd(&gsum[curg * 128 + c], ps);
            ps = 0.f; curg = g;
        }
        float v = h2[(size_t)r * 128 + c];
        s += v; s2 += v * v; ps += v;
    }
    atomicAdd(&gsum[curg * 128 + c], ps);
    atomicAdd(&sums[c], s);
    atomicAdd(&sums[128 + c], s2);
}

__global__ void bn_finalize(const float* __restrict__ sums,
                            const float* __restrict__ gamma, const float* __restrict__ beta,
                            int layer, float* __restrict__ coef /*[256] this layer*/) {
    int c = threadIdx.x;  // 128 threads
    float mean = sums[c] / (float)N_NODES;
    float var  = sums[128 + c] / (float)N_NODES - mean * mean;
    float istd = rsqrtf(var + 1e-5f);
    float a = istd * gamma[layer * 128 + c];
    coef[c]       = a;
    coef[128 + c] = beta[layer * 128 + c] - mean * a;
}

// ---------- head: one block per graph; pooled mean reconstructed analytically ----------
__global__ __launch_bounds__(256) void head_kernel(
    const float* __restrict__ gsum /*[L][G*128]*/, const float* __restrict__ coefL /*[L][256]*/,
    const int* __restrict__ batch, const float* __restrict__ emb,
    const float* __restrict__ l1w, const float* __restrict__ l1b,
    const float* __restrict__ l2w, const float* __restrict__ l2b,
    const float* __restrict__ l4w, const float* __restrict__ l4b,
    float* __restrict__ out) {
    __shared__ float z[576];
    __shared__ float z1[256];
    __shared__ float z2[128];
    __shared__ float z3s[10];
    __shared__ float inv_cnt;
    int g = blockIdx.x;
    int tid = threadIdx.x;
    if (tid == 0) {
        int lo = 0, hi = N_NODES;
        while (lo < hi) { int m = (lo + hi) >> 1; if (batch[m] < g) lo = m + 1; else hi = m; }
        int s = lo;
        lo = 0; hi = N_NODES;
        while (lo < hi) { int m = (lo + hi) >> 1; if (batch[m] < g + 1) lo = m + 1; else hi = m; }
        inv_cnt = 1.0f / fmaxf((float)(lo - s), 1.0f);
    }
    __syncthreads();
    // z[l*128+c] = a_lc * (gsum/cnt) + d_lc
    for (int j = tid; j < 512; j += 256) {
        int l = j >> 7, c = j & 127;
        float a = coefL[l * 256 + c], d = coefL[l * 256 + 128 + c];
        z[j] = a * gsum[(size_t)l * NGRAPH * 128 + g * 128 + c] * inv_cnt + d;
    }
    if (tid < 64) z[512 + tid] = emb[g * 64 + tid];
    __syncthreads();
    {   // z1[256] = relu(z[576] @ l1w + b)
        float acc = l1b[tid];
        for (int j = 0; j < 576; j++) acc += z[j] * l1w[j * 256 + tid];
        z1[tid] = fmaxf(acc, 0.f);
    }
    __syncthreads();
    if (tid < 128) {
        float acc = l2b[tid];
        for (int j = 0; j < 256; j++) acc += z1[j] * l2w[j * 128 + tid];
        z2[tid] = fmaxf(acc, 0.f);
    }
    __syncthreads();
    if (tid < 10) {
        float acc = l4b[tid];
        for (int j = 0; j < 128; j++) acc += z2[j] * l4w[j * 10 + tid];
        z3s[tid] = acc;
    }
    __syncthreads();
    if (tid == 0) {
        float m = z3s[0];
        for (int i = 1; i < 10; i++) m = fmaxf(m, z3s[i]);
        float se = 0.f;
        for (int i = 0; i < 10; i++) se += expf(z3s[i] - m);
        float lse = m + logf(se);
        for (int i = 0; i < 10; i++) out[g * 10 + i] = z3s[i] - lse;
    }
}

extern "C" void kernel_launch(void* const* d_in, const int* in_sizes, int n_in,
                              void* d_out, int out_size, void* d_ws, size_t ws_size,
                              hipStream_t stream) {
    (void)in_sizes; (void)n_in; (void)out_size; (void)ws_size;
    const float* x0   = (const float*)d_in[0];
    const int* ei     = (const int*)d_in[1];
    const int* src    = ei;
    const int* dst    = ei + N_EDGES;
    const int* batch  = (const int*)d_in[2];
    const float* emb  = (const float*)d_in[3];
    const float* eps  = (const float*)d_in[4];
    const float* W1   = (const float*)d_in[5];
    const float* b1   = (const float*)d_in[6];
    const float* W2   = (const float*)d_in[7];
    const float* b2   = (const float*)d_in[8];
    const float* gamma= (const float*)d_in[9];
    const float* beta = (const float*)d_in[10];
    const float* l1w  = (const float*)d_in[11];
    const float* l1b  = (const float*)d_in[12];
    const float* l2w  = (const float*)d_in[13];
    const float* l2b  = (const float*)d_in[14];
    const float* l4w  = (const float*)d_in[15];
    const float* l4b  = (const float*)d_in[16];

    char* ws = (char*)d_ws;
    size_t off = 0;
    auto alloc = [&](size_t bytes) -> char* {
        char* p = ws + off; off += (bytes + 255) & ~(size_t)255; return p;
    };
    // zero-region 1: deg + cursor (contiguous)
    int* deg    = (int*)alloc(N_NODES * 4);
    int* cursor = (int*)ws + ((size_t)(N_NODES * 4 + 255) & ~(size_t)255) / 4; // == next alloc
    cursor      = (int*)alloc(N_NODES * 4);
    size_t zero1_off = (char*)deg - ws;
    size_t zero1_len = ((char*)cursor - (char*)deg) + ((N_NODES * 4 + 255) & ~(size_t)255);
    int* rowp   = (int*)alloc((N_NODES + 1) * 4);
    int* bscan  = (int*)alloc(N_NODES * 4);
    int* bsum   = (int*)alloc(SCAN_NB * 4);
    int* boff   = (int*)alloc(SCAN_NB * 4);
    int* col    = (int*)alloc(N_EDGES * 4);
    float* agg  = (float*)alloc((size_t)N_NODES * 128 * 4);
    float* h1   = (float*)alloc((size_t)N_NODES * 128 * 4);
    float* h2   = (float*)alloc((size_t)N_NODES * 128 * 4);
    // zero-region 2: sums[L][256] + gsum[L][G*128] (contiguous)
    float* sumsL = (float*)alloc(NLAYER * 256 * 4);
    float* gsumL = (float*)alloc((size_t)NLAYER * NGRAPH * 128 * 4);
    size_t zero2_off = (char*)sumsL - ws;
    size_t zero2_len = ((char*)gsumL - (char*)sumsL) + (size_t)NLAYER * NGRAPH * 128 * 4;
    float* coefL = (float*)alloc(NLAYER * 256 * 4);

    hipMemsetAsync(ws + zero1_off, 0, zero1_len, stream);
    hipMemsetAsync(ws + zero2_off, 0, zero2_len, stream);

    count_deg<<<(N_EDGES + 255) / 256, 256, 0, stream>>>(dst, deg);
    scan_l1<<<SCAN_NB, 256, 0, stream>>>(deg, bscan, bsum);
    scan_l2<<<1, 256, 0, stream>>>(bsum, boff);
    scan_l3<<<SCAN_NB, 256, 0, stream>>>(bscan, boff, rowp);
    fill_csr<<<(N_EDGES + 255) / 256, 256, 0, stream>>>(src, dst, rowp, cursor, col);

    const float* xin = x0;
    for (int l = 0; l < NLAYER; ++l) {
        const float* coef_prev = (l == 0) ? nullptr : (coefL + (l - 1) * 256);
        agg_kernel<<<(N_NODES + 3) / 4, 256, 0, stream>>>(
            (const float2*)xin, coef_prev, rowp, col, eps, l, (float2*)agg);
        dim3 gg((N_NODES + 63) / 64, 2);
        gemm_f32<true><<<gg, 256, 0, stream>>>(agg, W1 + (size_t)l * 128 * 128,
                                               b1 + l * 128, h1, N_NODES);
        gemm_f32<true><<<gg, 256, 0, stream>>>(h1, W2 + (size_t)l * 128 * 128,
                                               b2 + l * 128, h2, N_NODES);
        stats_pool<<<(N_NODES + 63) / 64, 128, 0, stream>>>(
            h2, batch, sumsL + l * 256, gsumL + (size_t)l * NGRAPH * 128);
        bn_finalize<<<1, 128, 0, stream>>>(sumsL + l * 256, gamma, beta, l,
                                           coefL + l * 256);
        xin = h2;  // next agg reads raw h2 and applies coef analytically
    }
    head_kernel<<<NGRAPH, 256, 0, stream>>>(gsumL, coefL, batch, emb,
                                            l1w, l1b, l2w, l2b, l4w, l4b,
                                            (float*)d_out);
}

// Round 4
// 691.838 us; speedup vs baseline: 1.7311x; 1.3768x over previous
//
#include <hip/hip_runtime.h>
#include <cstdint>
#include <cstddef>

#define N_NODES 50000
#define N_EDGES 600000
#define NLAYER  4
#define NGRAPH  64
#define SCAN_NB 196   // ceil(50000/256)

typedef unsigned int   u32;
typedef unsigned short u16;
typedef float f32x4  __attribute__((ext_vector_type(4)));
typedef short bf16x8 __attribute__((ext_vector_type(8)));

// ---------- bf16 helpers ----------
__device__ __forceinline__ float bf1(u16 u)  { return __uint_as_float(((u32)u) << 16); }
__device__ __forceinline__ float bflo(u32 u) { return __uint_as_float(u << 16); }
__device__ __forceinline__ float bfhi(u32 u) { return __uint_as_float(u & 0xffff0000u); }
__device__ __forceinline__ u16 f2bf(float f) {
    u32 x = __float_as_uint(f);
    u32 r = x + 0x7fffu + ((x >> 16) & 1u);   // RNE
    return (u16)(r >> 16);
}
__device__ __forceinline__ u32 pack2(float a, float b) {
    return (u32)f2bf(a) | ((u32)f2bf(b) << 16);
}

// ---------- dtype conversion ----------
__global__ __launch_bounds__(256) void cvt_x(const float2* __restrict__ x,
                                             u32* __restrict__ xbf) {
    int i = blockIdx.x * 256 + threadIdx.x;   // over N*64 float2s
    if (i < N_NODES * 64) { float2 v = x[i]; xbf[i] = pack2(v.x, v.y); }
}

// W: [L][128 k][128 n] fp32 -> Wt: [L][128 n][128 k] bf16
__global__ __launch_bounds__(128) void cvt_w(const float* __restrict__ W,
                                             short* __restrict__ Wt) {
    int l = blockIdx.y, n = blockIdx.x, k = threadIdx.x;
    Wt[((size_t)l * 128 + n) * 128 + k] = (short)f2bf(W[((size_t)l * 128 + k) * 128 + n]);
}

// ---------- CSR build ----------
__global__ void count_deg(const int* __restrict__ dst, int* __restrict__ deg) {
    int e = blockIdx.x * 256 + threadIdx.x;
    if (e < N_EDGES) atomicAdd(&deg[dst[e]], 1);
}

__global__ __launch_bounds__(256) void scan_l1(const int* __restrict__ deg,
                                               int* __restrict__ bscan,
                                               int* __restrict__ bsum) {
    __shared__ int sd[256];
    int tid = threadIdx.x;
    int i = blockIdx.x * 256 + tid;
    int v = (i < N_NODES) ? deg[i] : 0;
    sd[tid] = v; __syncthreads();
#pragma unroll
    for (int off = 1; off < 256; off <<= 1) {
        int t = (tid >= off) ? sd[tid - off] : 0;
        __syncthreads();
        sd[tid] += t; __syncthreads();
    }
    if (i < N_NODES) bscan[i] = sd[tid];
    if (tid == 255) bsum[blockIdx.x] = sd[255];
}

__global__ __launch_bounds__(256) void scan_l2(const int* __restrict__ bsum,
                                               int* __restrict__ boff) {
    __shared__ int sd[256];
    int tid = threadIdx.x;
    int v = (tid < SCAN_NB) ? bsum[tid] : 0;
    sd[tid] = v; __syncthreads();
#pragma unroll
    for (int off = 1; off < 256; off <<= 1) {
        int t = (tid >= off) ? sd[tid - off] : 0;
        __syncthreads();
        sd[tid] += t; __syncthreads();
    }
    if (tid < SCAN_NB) boff[tid] = sd[tid] - v;
}

__global__ __launch_bounds__(256) void scan_l3(const int* __restrict__ bscan,
                                               const int* __restrict__ boff,
                                               int* __restrict__ rowp) {
    int i = blockIdx.x * 256 + threadIdx.x;
    if (i == 0) rowp[0] = 0;
    if (i < N_NODES) rowp[i + 1] = bscan[i] + boff[blockIdx.x];
}

__global__ void fill_csr(const int* __restrict__ src, const int* __restrict__ dst,
                         const int* __restrict__ rowp, int* __restrict__ cursor,
                         int* __restrict__ col) {
    int e = blockIdx.x * 256 + threadIdx.x;
    if (e < N_EDGES) {
        int d = dst[e];
        int pos = atomicAdd(&cursor[d], 1);
        col[rowp[d] + pos] = src[e];
    }
}

// ---------- GIN aggregation (bf16 in/out, fp32 accum, analytic BN of prev layer) ----------
// agg[i] = (1+eps)*(a*x_i+d) + a*sum_j x_j + deg_i*d
__global__ __launch_bounds__(256) void agg_kernel(
    const u32* __restrict__ xin,      // [N][64] u32 (128 bf16)
    const float* __restrict__ coef,   // nullable [256]
    const int* __restrict__ rowp, const int* __restrict__ col,
    const float* __restrict__ eps_all, int layer,
    u32* __restrict__ agg) {
    int node = blockIdx.x * 4 + (threadIdx.x >> 6);
    int lane = threadIdx.x & 63;
    if (node >= N_NODES) return;
    float a0 = 1.f, a1 = 1.f, d0 = 0.f, d1 = 0.f;
    if (coef) {
        a0 = coef[2 * lane];       a1 = coef[2 * lane + 1];
        d0 = coef[128 + 2 * lane]; d1 = coef[128 + 2 * lane + 1];
    }
    float ep = 1.0f + eps_all[layer];
    u32 v = xin[(size_t)node * 64 + lane];
    int k0 = rowp[node], k1 = rowp[node + 1];
    float s0 = 0.f, s1 = 0.f;
    for (int k = k0; k < k1; ++k) {
        int s = col[k];
        u32 u = xin[(size_t)s * 64 + lane];
        s0 += bflo(u); s1 += bfhi(u);
    }
    float deg = (float)(k1 - k0);
    float r0 = ep * (a0 * bflo(v) + d0) + a0 * s0 + deg * d0;
    float r1 = ep * (a1 * bfhi(v) + d1) + a1 * s1 + deg * d1;
    agg[(size_t)node * 64 + lane] = pack2(r0, r1);
}

// ---------- fused MLP: h2 = relu(relu(A@W1+b1)@W2+b2), bf16 MFMA, h1 in LDS ----------
// block = 128 rows, 4 waves x 32 rows. Wt are n-major ([n][k]).
#define H1_STRIDE 136   // shorts per LDS row (128 + 8 pad -> 272B, 16B aligned)
__global__ __launch_bounds__(256) void mlp_fused(
    const short* __restrict__ A,      // [M][128] bf16
    const short* __restrict__ W1t, const float* __restrict__ b1,
    const short* __restrict__ W2t, const float* __restrict__ b2,
    short* __restrict__ H2, int M) {
    __shared__ short h1s[128 * H1_STRIDE];
    int tid  = threadIdx.x;
    int wave = tid >> 6, lane = tid & 63;
    int ln15 = lane & 15, quad = lane >> 4;
    int m0 = blockIdx.x * 128 + wave * 32;
    const bf16x8 zz = {0, 0, 0, 0, 0, 0, 0, 0};

    // A-frags for GEMM1, straight from global (block is sole reader of its rows)
    bf16x8 a[2][4];
#pragma unroll
    for (int rt = 0; rt < 2; rt++) {
        int row = m0 + rt * 16 + ln15;
        const short* rp = A + (size_t)row * 128 + quad * 8;
        bool ok = row < M;
#pragma unroll
        for (int s = 0; s < 4; s++)
            a[rt][s] = ok ? *(const bf16x8*)(rp + s * 32) : zz;
    }
    // GEMM1 -> h1 (LDS, bf16)
#pragma unroll
    for (int ct = 0; ct < 8; ct++) {
        const short* wp = W1t + (size_t)(ct * 16 + ln15) * 128 + quad * 8;
        bf16x8 b[4];
#pragma unroll
        for (int s = 0; s < 4; s++) b[s] = *(const bf16x8*)(wp + s * 32);
        float bias = b1[ct * 16 + ln15];
#pragma unroll
        for (int rt = 0; rt < 2; rt++) {
            f32x4 acc = {0.f, 0.f, 0.f, 0.f};
#pragma unroll
            for (int s = 0; s < 4; s++)
                acc = __builtin_amdgcn_mfma_f32_16x16x32_bf16(a[rt][s], b[s], acc, 0, 0, 0);
#pragma unroll
            for (int i = 0; i < 4; i++) {
                float v = fmaxf(acc[i] + bias, 0.f);
                int lr = wave * 32 + rt * 16 + quad * 4 + i;   // C row = quad*4+i
                h1s[lr * H1_STRIDE + ct * 16 + ln15] = (short)f2bf(v);
            }
        }
    }
    __syncthreads();
    // A-frags for GEMM2 from LDS (wave reads only its own 32 rows)
    bf16x8 c[2][4];
#pragma unroll
    for (int rt = 0; rt < 2; rt++) {
        const short* rp = h1s + (size_t)(wave * 32 + rt * 16 + ln15) * H1_STRIDE + quad * 8;
#pragma unroll
        for (int s = 0; s < 4; s++) c[rt][s] = *(const bf16x8*)(rp + s * 32);
    }
    // GEMM2 -> H2 (global, bf16)
#pragma unroll
    for (int ct = 0; ct < 8; ct++) {
        const short* wp = W2t + (size_t)(ct * 16 + ln15) * 128 + quad * 8;
        bf16x8 b[4];
#pragma unroll
        for (int s = 0; s < 4; s++) b[s] = *(const bf16x8*)(wp + s * 32);
        float bias = b2[ct * 16 + ln15];
#pragma unroll
        for (int rt = 0; rt < 2; rt++) {
            f32x4 acc = {0.f, 0.f, 0.f, 0.f};
#pragma unroll
            for (int s = 0; s < 4; s++)
                acc = __builtin_amdgcn_mfma_f32_16x16x32_bf16(c[rt][s], b[s], acc, 0, 0, 0);
            int col = ct * 16 + ln15;
#pragma unroll
            for (int i = 0; i < 4; i++) {
                int row = m0 + rt * 16 + quad * 4 + i;
                if (row < M) {
                    float v = fmaxf(acc[i] + bias, 0.f);
                    H2[(size_t)row * 128 + col] = (short)f2bf(v);
                }
            }
        }
    }
}

// ---------- fused BN stats + per-graph raw sums (batch sorted), bf16 input ----------
__global__ __launch_bounds__(128) void stats_pool(
    const u16* __restrict__ h2, const int* __restrict__ batch,
    float* __restrict__ sums /*[256]*/, float* __restrict__ gsum /*[G*128]*/) {
    int c = threadIdx.x;
    int r0 = blockIdx.x * 64;
    int r1 = min(r0 + 64, N_NODES);
    float s = 0.f, s2 = 0.f, ps = 0.f;
    int curg = batch[r0];
    for (int r = r0; r < r1; ++r) {
        int g = batch[r];
        if (g != curg) {
            atomicAdd(&gsum[curg * 128 + c], ps);
            ps = 0.f; curg = g;
        }
        float v = bf1(h2[(size_t)r * 128 + c]);
        s += v; s2 += v * v; ps += v;
    }
    atomicAdd(&gsum[curg * 128 + c], ps);
    atomicAdd(&sums[c], s);
    atomicAdd(&sums[128 + c], s2);
}

__global__ void bn_finalize(const float* __restrict__ sums,
                            const float* __restrict__ gamma, const float* __restrict__ beta,
                            int layer, float* __restrict__ coef) {
    int c = threadIdx.x;  // 128
    float mean = sums[c] / (float)N_NODES;
    float var  = sums[128 + c] / (float)N_NODES - mean * mean;
    float istd = rsqrtf(var + 1e-5f);
    float a = istd * gamma[layer * 128 + c];
    coef[c]       = a;
    coef[128 + c] = beta[layer * 128 + c] - mean * a;
}

// ---------- head ----------
__global__ __launch_bounds__(256) void head_kernel(
    const float* __restrict__ gsum, const float* __restrict__ coefL,
    const int* __restrict__ batch, const float* __restrict__ emb,
    const float* __restrict__ l1w, const float* __restrict__ l1b,
    const float* __restrict__ l2w, const float* __restrict__ l2b,
    const float* __restrict__ l4w, const float* __restrict__ l4b,
    float* __restrict__ out) {
    __shared__ float z[576];
    __shared__ float z1[256];
    __shared__ float z2[128];
    __shared__ float z3s[10];
    __shared__ float inv_cnt;
    int g = blockIdx.x;
    int tid = threadIdx.x;
    if (tid == 0) {
        int lo = 0, hi = N_NODES;
        while (lo < hi) { int m = (lo + hi) >> 1; if (batch[m] < g) lo = m + 1; else hi = m; }
        int s = lo;
        lo = 0; hi = N_NODES;
        while (lo < hi) { int m = (lo + hi) >> 1; if (batch[m] < g + 1) lo = m + 1; else hi = m; }
        inv_cnt = 1.0f / fmaxf((float)(lo - s), 1.0f);
    }
    __syncthreads();
    for (int j = tid; j < 512; j += 256) {
        int l = j >> 7, c = j & 127;
        float a = coefL[l * 256 + c], d = coefL[l * 256 + 128 + c];
        z[j] = a * gsum[(size_t)l * NGRAPH * 128 + g * 128 + c] * inv_cnt + d;
    }
    if (tid < 64) z[512 + tid] = emb[g * 64 + tid];
    __syncthreads();
    {
        float acc = l1b[tid];
        for (int j = 0; j < 576; j++) acc += z[j] * l1w[j * 256 + tid];
        z1[tid] = fmaxf(acc, 0.f);
    }
    __syncthreads();
    if (tid < 128) {
        float acc = l2b[tid];
        for (int j = 0; j < 256; j++) acc += z1[j] * l2w[j * 128 + tid];
        z2[tid] = fmaxf(acc, 0.f);
    }
    __syncthreads();
    if (tid < 10) {
        float acc = l4b[tid];
        for (int j = 0; j < 128; j++) acc += z2[j] * l4w[j * 10 + tid];
        z3s[tid] = acc;
    }
    __syncthreads();
    if (tid == 0) {
        float m = z3s[0];
        for (int i = 1; i < 10; i++) m = fmaxf(m, z3s[i]);
        float se = 0.f;
        for (int i = 0; i < 10; i++) se += expf(z3s[i] - m);
        float lse = m + logf(se);
        for (int i = 0; i < 10; i++) out[g * 10 + i] = z3s[i] - lse;
    }
}

extern "C" void kernel_launch(void* const* d_in, const int* in_sizes, int n_in,
                              void* d_out, int out_size, void* d_ws, size_t ws_size,
                              hipStream_t stream) {
    (void)in_sizes; (void)n_in; (void)out_size; (void)ws_size;
    const float* x0   = (const float*)d_in[0];
    const int* ei     = (const int*)d_in[1];
    const int* src    = ei;
    const int* dst    = ei + N_EDGES;
    const int* batch  = (const int*)d_in[2];
    const float* emb  = (const float*)d_in[3];
    const float* eps  = (const float*)d_in[4];
    const float* W1   = (const float*)d_in[5];
    const float* b1   = (const float*)d_in[6];
    const float* W2   = (const float*)d_in[7];
    const float* b2   = (const float*)d_in[8];
    const float* gamma= (const float*)d_in[9];
    const float* beta = (const float*)d_in[10];
    const float* l1w  = (const float*)d_in[11];
    const float* l1b  = (const float*)d_in[12];
    const float* l2w  = (const float*)d_in[13];
    const float* l2b  = (const float*)d_in[14];
    const float* l4w  = (const float*)d_in[15];
    const float* l4b  = (const float*)d_in[16];

    char* ws = (char*)d_ws;
    size_t off = 0;
    auto alloc = [&](size_t bytes) -> char* {
        char* p = ws + off; off += (bytes + 255) & ~(size_t)255; return p;
    };
    // zero-region 1: deg + cursor (contiguous)
    int* deg    = (int*)alloc(N_NODES * 4);
    int* cursor = (int*)alloc(N_NODES * 4);
    size_t zero1_len = (char*)cursor - (char*)deg + (((size_t)N_NODES * 4 + 255) & ~(size_t)255);
    int* rowp   = (int*)alloc((N_NODES + 1) * 4);
    int* bscan  = (int*)alloc(N_NODES * 4);
    int* bsum   = (int*)alloc(SCAN_NB * 4);
    int* boff   = (int*)alloc(SCAN_NB * 4);
    int* col    = (int*)alloc(N_EDGES * 4);
    u32* xbf    = (u32*)alloc((size_t)N_NODES * 64 * 4);   // x in bf16
    u32* agg    = (u32*)alloc((size_t)N_NODES * 64 * 4);   // bf16
    u32* h2a    = (u32*)alloc((size_t)N_NODES * 64 * 4);   // bf16
    u32* h2b    = (u32*)alloc((size_t)N_NODES * 64 * 4);   // bf16
    short* W1t  = (short*)alloc((size_t)NLAYER * 128 * 128 * 2);
    short* W2t  = (short*)alloc((size_t)NLAYER * 128 * 128 * 2);
    // zero-region 2: sums + gsum (contiguous)
    float* sumsL = (float*)alloc(NLAYER * 256 * 4);
    float* gsumL = (float*)alloc((size_t)NLAYER * NGRAPH * 128 * 4);
    size_t zero2_len = (char*)gsumL - (char*)sumsL + (size_t)NLAYER * NGRAPH * 128 * 4;
    float* coefL = (float*)alloc(NLAYER * 256 * 4);

    hipMemsetAsync(deg, 0, zero1_len, stream);
    hipMemsetAsync(sumsL, 0, zero2_len, stream);

    cvt_x<<<(N_NODES * 64 + 255) / 256, 256, 0, stream>>>((const float2*)x0, xbf);
    {
        dim3 gw(128, NLAYER);
        cvt_w<<<gw, 128, 0, stream>>>(W1, W1t);
        cvt_w<<<gw, 128, 0, stream>>>(W2, W2t);
    }
    count_deg<<<(N_EDGES + 255) / 256, 256, 0, stream>>>(dst, deg);
    scan_l1<<<SCAN_NB, 256, 0, stream>>>(deg, bscan, bsum);
    scan_l2<<<1, 256, 0, stream>>>(bsum, boff);
    scan_l3<<<SCAN_NB, 256, 0, stream>>>(bscan, boff, rowp);
    fill_csr<<<(N_EDGES + 255) / 256, 256, 0, stream>>>(src, dst, rowp, cursor, col);

    const u32* xin = xbf;
    for (int l = 0; l < NLAYER; ++l) {
        u32* h2 = (l & 1) ? h2b : h2a;
        const float* coef_prev = (l == 0) ? nullptr : (coefL + (l - 1) * 256);
        agg_kernel<<<(N_NODES + 3) / 4, 256, 0, stream>>>(
            xin, coef_prev, rowp, col, eps, l, agg);
        mlp_fused<<<(N_NODES + 127) / 128, 256, 0, stream>>>(
            (const short*)agg, W1t + (size_t)l * 16384, b1 + l * 128,
            W2t + (size_t)l * 16384, b2 + l * 128, (short*)h2, N_NODES);
        stats_pool<<<(N_NODES + 63) / 64, 128, 0, stream>>>(
            (const u16*)h2, batch, sumsL + l * 256, gsumL + (size_t)l * NGRAPH * 128);
        bn_finalize<<<1, 128, 0, stream>>>(sumsL + l * 256, gamma, beta, l,
                                           coefL + l * 256);
        xin = h2;
    }
    head_kernel<<<NGRAPH, 256, 0, stream>>>(gsumL, coefL, batch, emb,
                                            l1w, l1b, l2w, l2b, l4w, l4b,
                                            (float*)d_out);
}

// Round 5
// 657.937 us; speedup vs baseline: 1.8203x; 1.0515x over previous
//
#include <hip/hip_runtime.h>
#include <cstdint>
#include <cstddef>

#define N_NODES 50000
#define N_EDGES 600000
#define NLAYER  4
#define NGRAPH  64
#define SCAN_NB 196   // ceil(50000/256)

typedef unsigned int   u32;
typedef unsigned short u16;
typedef float f32x4  __attribute__((ext_vector_type(4)));
typedef short bf16x8 __attribute__((ext_vector_type(8)));

// ---------- bf16 helpers ----------
__device__ __forceinline__ float bf1(u16 u)  { return __uint_as_float(((u32)u) << 16); }
__device__ __forceinline__ float bflo(u32 u) { return __uint_as_float(u << 16); }
__device__ __forceinline__ float bfhi(u32 u) { return __uint_as_float(u & 0xffff0000u); }
__device__ __forceinline__ u16 f2bf(float f) {
    u32 x = __float_as_uint(f);
    u32 r = x + 0x7fffu + ((x >> 16) & 1u);   // RNE
    return (u16)(r >> 16);
}
__device__ __forceinline__ u32 pack2(float a, float b) {
    return (u32)f2bf(a) | ((u32)f2bf(b) << 16);
}

// ---------- dtype conversion ----------
__global__ __launch_bounds__(256) void cvt_x(const float2* __restrict__ x,
                                             u32* __restrict__ xbf) {
    int i = blockIdx.x * 256 + threadIdx.x;   // over N*64 float2s
    if (i < N_NODES * 64) { float2 v = x[i]; xbf[i] = pack2(v.x, v.y); }
}

// W: [L][128 k][128 n] fp32 -> Wt: [L][128 n][128 k] bf16; z selects W1/W2
__global__ __launch_bounds__(128) void cvt_w(const float* __restrict__ W1,
                                             const float* __restrict__ W2,
                                             short* __restrict__ W1t,
                                             short* __restrict__ W2t) {
    int l = blockIdx.y, n = blockIdx.x, k = threadIdx.x;
    const float* W = blockIdx.z ? W2 : W1;
    short* Wt      = blockIdx.z ? W2t : W1t;
    Wt[((size_t)l * 128 + n) * 128 + k] = (short)f2bf(W[((size_t)l * 128 + k) * 128 + n]);
}

// ---------- CSR build ----------
__global__ void count_deg(const int* __restrict__ dst, int* __restrict__ deg) {
    int e = blockIdx.x * 256 + threadIdx.x;
    if (e < N_EDGES) atomicAdd(&deg[dst[e]], 1);
}

__global__ __launch_bounds__(256) void scan_l1(const int* __restrict__ deg,
                                               int* __restrict__ bscan,
                                               int* __restrict__ bsum) {
    __shared__ int sd[256];
    int tid = threadIdx.x;
    int i = blockIdx.x * 256 + tid;
    int v = (i < N_NODES) ? deg[i] : 0;
    sd[tid] = v; __syncthreads();
#pragma unroll
    for (int off = 1; off < 256; off <<= 1) {
        int t = (tid >= off) ? sd[tid - off] : 0;
        __syncthreads();
        sd[tid] += t; __syncthreads();
    }
    if (i < N_NODES) bscan[i] = sd[tid];
    if (tid == 255) bsum[blockIdx.x] = sd[255];
}

__global__ __launch_bounds__(256) void scan_l2(const int* __restrict__ bsum,
                                               int* __restrict__ boff) {
    __shared__ int sd[256];
    int tid = threadIdx.x;
    int v = (tid < SCAN_NB) ? bsum[tid] : 0;
    sd[tid] = v; __syncthreads();
#pragma unroll
    for (int off = 1; off < 256; off <<= 1) {
        int t = (tid >= off) ? sd[tid - off] : 0;
        __syncthreads();
        sd[tid] += t; __syncthreads();
    }
    if (tid < SCAN_NB) boff[tid] = sd[tid] - v;
}

__global__ __launch_bounds__(256) void scan_l3(const int* __restrict__ bscan,
                                               const int* __restrict__ boff,
                                               int* __restrict__ rowp) {
    int i = blockIdx.x * 256 + threadIdx.x;
    if (i == 0) rowp[0] = 0;
    if (i < N_NODES) rowp[i + 1] = bscan[i] + boff[blockIdx.x];
}

__global__ void fill_csr(const int* __restrict__ src, const int* __restrict__ dst,
                         const int* __restrict__ rowp, int* __restrict__ cursor,
                         int* __restrict__ col) {
    int e = blockIdx.x * 256 + threadIdx.x;
    if (e < N_EDGES) {
        int d = dst[e];
        int pos = atomicAdd(&cursor[d], 1);
        col[rowp[d] + pos] = src[e];
    }
}

// ---------- GIN aggregation (bf16, fp32 accum, analytic BN of prev layer) ----------
// agg[i] = (1+eps)*(a*x_i+d) + a*sum_j x_j + deg_i*d
// one wave per node; 4-wide software-pipelined edge loop (~4 gathers in flight)
__global__ __launch_bounds__(256) void agg_kernel(
    const u32* __restrict__ xin,      // [N][64] u32 (128 bf16)
    const float* __restrict__ coef,   // nullable [256]
    const int* __restrict__ rowp, const int* __restrict__ col,
    const float* __restrict__ eps_all, int layer,
    u32* __restrict__ agg) {
    int node = blockIdx.x * 4 + (threadIdx.x >> 6);
    int lane = threadIdx.x & 63;
    if (node >= N_NODES) return;
    float a0 = 1.f, a1 = 1.f, d0 = 0.f, d1 = 0.f;
    if (coef) {
        a0 = coef[2 * lane];       a1 = coef[2 * lane + 1];
        d0 = coef[128 + 2 * lane]; d1 = coef[128 + 2 * lane + 1];
    }
    float ep = 1.0f + eps_all[layer];
    u32 v = xin[(size_t)node * 64 + lane];
    int k0 = rowp[node], k1 = rowp[node + 1];
    int n = k1 - k0;
    int k = k0;
    float s0 = 0.f, s1 = 0.f;
    int c0 = 0, c1 = 0, c2 = 0, c3 = 0;
    if (n >= 4) { c0 = col[k]; c1 = col[k + 1]; c2 = col[k + 2]; c3 = col[k + 3]; }
    while (n >= 4) {
        int i0 = c0, i1 = c1, i2 = c2, i3 = c3;
        k += 4; n -= 4;
        if (n >= 4) { c0 = col[k]; c1 = col[k + 1]; c2 = col[k + 2]; c3 = col[k + 3]; }
        u32 u0 = xin[(size_t)i0 * 64 + lane];
        u32 u1 = xin[(size_t)i1 * 64 + lane];
        u32 u2 = xin[(size_t)i2 * 64 + lane];
        u32 u3 = xin[(size_t)i3 * 64 + lane];
        s0 += (bflo(u0) + bflo(u1)) + (bflo(u2) + bflo(u3));
        s1 += (bfhi(u0) + bfhi(u1)) + (bfhi(u2) + bfhi(u3));
    }
    while (n > 0) {
        int s = col[k++]; --n;
        u32 u = xin[(size_t)s * 64 + lane];
        s0 += bflo(u); s1 += bfhi(u);
    }
    float deg = (float)(k1 - k0);
    float r0 = ep * (a0 * bflo(v) + d0) + a0 * s0 + deg * d0;
    float r1 = ep * (a1 * bfhi(v) + d1) + a1 * s1 + deg * d1;
    agg[(size_t)node * 64 + lane] = pack2(r0, r1);
}

// ---------- fused MLP: h2 = relu(relu(A@W1+b1)@W2+b2), bf16 MFMA, h1 in LDS ----------
#define H1_STRIDE 136   // shorts per LDS row (128 + 8 pad -> 272B, 16B aligned)
__global__ __launch_bounds__(256) void mlp_fused(
    const short* __restrict__ A,      // [M][128] bf16
    const short* __restrict__ W1t, const float* __restrict__ b1,
    const short* __restrict__ W2t, const float* __restrict__ b2,
    short* __restrict__ H2, int M) {
    __shared__ short h1s[128 * H1_STRIDE];
    int tid  = threadIdx.x;
    int wave = tid >> 6, lane = tid & 63;
    int ln15 = lane & 15, quad = lane >> 4;
    int m0 = blockIdx.x * 128 + wave * 32;
    const bf16x8 zz = {0, 0, 0, 0, 0, 0, 0, 0};

    bf16x8 a[2][4];
#pragma unroll
    for (int rt = 0; rt < 2; rt++) {
        int row = m0 + rt * 16 + ln15;
        const short* rp = A + (size_t)row * 128 + quad * 8;
        bool ok = row < M;
#pragma unroll
        for (int s = 0; s < 4; s++)
            a[rt][s] = ok ? *(const bf16x8*)(rp + s * 32) : zz;
    }
#pragma unroll
    for (int ct = 0; ct < 8; ct++) {
        const short* wp = W1t + (size_t)(ct * 16 + ln15) * 128 + quad * 8;
        bf16x8 b[4];
#pragma unroll
        for (int s = 0; s < 4; s++) b[s] = *(const bf16x8*)(wp + s * 32);
        float bias = b1[ct * 16 + ln15];
#pragma unroll
        for (int rt = 0; rt < 2; rt++) {
            f32x4 acc = {0.f, 0.f, 0.f, 0.f};
#pragma unroll
            for (int s = 0; s < 4; s++)
                acc = __builtin_amdgcn_mfma_f32_16x16x32_bf16(a[rt][s], b[s], acc, 0, 0, 0);
#pragma unroll
            for (int i = 0; i < 4; i++) {
                float v = fmaxf(acc[i] + bias, 0.f);
                int lr = wave * 32 + rt * 16 + quad * 4 + i;
                h1s[lr * H1_STRIDE + ct * 16 + ln15] = (short)f2bf(v);
            }
        }
    }
    __syncthreads();
    bf16x8 c[2][4];
#pragma unroll
    for (int rt = 0; rt < 2; rt++) {
        const short* rp = h1s + (size_t)(wave * 32 + rt * 16 + ln15) * H1_STRIDE + quad * 8;
#pragma unroll
        for (int s = 0; s < 4; s++) c[rt][s] = *(const bf16x8*)(rp + s * 32);
    }
#pragma unroll
    for (int ct = 0; ct < 8; ct++) {
        const short* wp = W2t + (size_t)(ct * 16 + ln15) * 128 + quad * 8;
        bf16x8 b[4];
#pragma unroll
        for (int s = 0; s < 4; s++) b[s] = *(const bf16x8*)(wp + s * 32);
        float bias = b2[ct * 16 + ln15];
#pragma unroll
        for (int rt = 0; rt < 2; rt++) {
            f32x4 acc = {0.f, 0.f, 0.f, 0.f};
#pragma unroll
            for (int s = 0; s < 4; s++)
                acc = __builtin_amdgcn_mfma_f32_16x16x32_bf16(c[rt][s], b[s], acc, 0, 0, 0);
            int colx = ct * 16 + ln15;
#pragma unroll
            for (int i = 0; i < 4; i++) {
                int row = m0 + rt * 16 + quad * 4 + i;
                if (row < M) {
                    float v = fmaxf(acc[i] + bias, 0.f);
                    H2[(size_t)row * 128 + colx] = (short)f2bf(v);
                }
            }
        }
    }
}

// ---------- fused BN stats + per-graph raw sums (batch sorted), u32 loads ----------
// block = 128 threads = 2 waves; each wave covers 64 rows, lane = col-pair
__global__ __launch_bounds__(128) void stats_pool(
    const u32* __restrict__ h2, const int* __restrict__ batch,
    float* __restrict__ sums /*[256]*/, float* __restrict__ gsum /*[G*128]*/) {
    int lane = threadIdx.x & 63;
    int wave = threadIdx.x >> 6;
    int r0 = blockIdx.x * 128 + wave * 64;
    if (r0 >= N_NODES) return;
    int r1 = min(r0 + 64, N_NODES);
    float s0 = 0.f, s1 = 0.f, q0 = 0.f, q1 = 0.f, p0 = 0.f, p1 = 0.f;
    int curg = batch[r0];
    for (int r = r0; r < r1; ++r) {
        int g = batch[r];
        if (g != curg) {
            atomicAdd(&gsum[curg * 128 + 2 * lane],     p0);
            atomicAdd(&gsum[curg * 128 + 2 * lane + 1], p1);
            p0 = p1 = 0.f; curg = g;
        }
        u32 u = h2[(size_t)r * 64 + lane];
        float a = bflo(u), b = bfhi(u);
        s0 += a; s1 += b; q0 += a * a; q1 += b * b; p0 += a; p1 += b;
    }
    atomicAdd(&gsum[curg * 128 + 2 * lane],     p0);
    atomicAdd(&gsum[curg * 128 + 2 * lane + 1], p1);
    atomicAdd(&sums[2 * lane],           s0);
    atomicAdd(&sums[2 * lane + 1],       s1);
    atomicAdd(&sums[128 + 2 * lane],     q0);
    atomicAdd(&sums[128 + 2 * lane + 1], q1);
}

__global__ void bn_finalize(const float* __restrict__ sums,
                            const float* __restrict__ gamma, const float* __restrict__ beta,
                            int layer, float* __restrict__ coef) {
    int c = threadIdx.x;  // 128
    float mean = sums[c] / (float)N_NODES;
    float var  = sums[128 + c] / (float)N_NODES - mean * mean;
    float istd = rsqrtf(var + 1e-5f);
    float a = istd * gamma[layer * 128 + c];
    coef[c]       = a;
    coef[128 + c] = beta[layer * 128 + c] - mean * a;
}

// ---------- head ----------
__global__ __launch_bounds__(256) void head_kernel(
    const float* __restrict__ gsum, const float* __restrict__ coefL,
    const int* __restrict__ batch, const float* __restrict__ emb,
    const float* __restrict__ l1w, const float* __restrict__ l1b,
    const float* __restrict__ l2w, const float* __restrict__ l2b,
    const float* __restrict__ l4w, const float* __restrict__ l4b,
    float* __restrict__ out) {
    __shared__ float z[576];
    __shared__ float z1[256];
    __shared__ float z2[128];
    __shared__ float z3s[10];
    __shared__ float inv_cnt;
    int g = blockIdx.x;
    int tid = threadIdx.x;
    if (tid == 0) {
        int lo = 0, hi = N_NODES;
        while (lo < hi) { int m = (lo + hi) >> 1; if (batch[m] < g) lo = m + 1; else hi = m; }
        int s = lo;
        lo = 0; hi = N_NODES;
        while (lo < hi) { int m = (lo + hi) >> 1; if (batch[m] < g + 1) lo = m + 1; else hi = m; }
        inv_cnt = 1.0f / fmaxf((float)(lo - s), 1.0f);
    }
    __syncthreads();
    for (int j = tid; j < 512; j += 256) {
        int l = j >> 7, c = j & 127;
        float a = coefL[l * 256 + c], d = coefL[l * 256 + 128 + c];
        z[j] = a * gsum[(size_t)l * NGRAPH * 128 + g * 128 + c] * inv_cnt + d;
    }
    if (tid < 64) z[512 + tid] = emb[g * 64 + tid];
    __syncthreads();
    {
        float acc = l1b[tid];
        for (int j = 0; j < 576; j++) acc += z[j] * l1w[j * 256 + tid];
        z1[tid] = fmaxf(acc, 0.f);
    }
    __syncthreads();
    if (tid < 128) {
        float acc = l2b[tid];
        for (int j = 0; j < 256; j++) acc += z1[j] * l2w[j * 128 + tid];
        z2[tid] = fmaxf(acc, 0.f);
    }
    __syncthreads();
    if (tid < 10) {
        float acc = l4b[tid];
        for (int j = 0; j < 128; j++) acc += z2[j] * l4w[j * 10 + tid];
        z3s[tid] = acc;
    }
    __syncthreads();
    if (tid == 0) {
        float m = z3s[0];
        for (int i = 1; i < 10; i++) m = fmaxf(m, z3s[i]);
        float se = 0.f;
        for (int i = 0; i < 10; i++) se += expf(z3s[i] - m);
        float lse = m + logf(se);
        for (int i = 0; i < 10; i++) out[g * 10 + i] = z3s[i] - lse;
    }
}

extern "C" void kernel_launch(void* const* d_in, const int* in_sizes, int n_in,
                              void* d_out, int out_size, void* d_ws, size_t ws_size,
                              hipStream_t stream) {
    (void)in_sizes; (void)n_in; (void)out_size; (void)ws_size;
    const float* x0   = (const float*)d_in[0];
    const int* ei     = (const int*)d_in[1];
    const int* src    = ei;
    const int* dst    = ei + N_EDGES;
    const int* batch  = (const int*)d_in[2];
    const float* emb  = (const float*)d_in[3];
    const float* eps  = (const float*)d_in[4];
    const float* W1   = (const float*)d_in[5];
    const float* b1   = (const float*)d_in[6];
    const float* W2   = (const float*)d_in[7];
    const float* b2   = (const float*)d_in[8];
    const float* gamma= (const float*)d_in[9];
    const float* beta = (const float*)d_in[10];
    const float* l1w  = (const float*)d_in[11];
    const float* l1b  = (const float*)d_in[12];
    const float* l2w  = (const float*)d_in[13];
    const float* l2b  = (const float*)d_in[14];
    const float* l4w  = (const float*)d_in[15];
    const float* l4b  = (const float*)d_in[16];

    char* ws = (char*)d_ws;
    size_t off = 0;
    auto alloc = [&](size_t bytes) -> char* {
        char* p = ws + off; off += (bytes + 255) & ~(size_t)255; return p;
    };
    int* deg    = (int*)alloc(N_NODES * 4);
    int* cursor = (int*)alloc(N_NODES * 4);
    size_t zero1_len = (char*)cursor - (char*)deg + (((size_t)N_NODES * 4 + 255) & ~(size_t)255);
    int* rowp   = (int*)alloc((N_NODES + 1) * 4);
    int* bscan  = (int*)alloc(N_NODES * 4);
    int* bsum   = (int*)alloc(SCAN_NB * 4);
    int* boff   = (int*)alloc(SCAN_NB * 4);
    int* col    = (int*)alloc(N_EDGES * 4);
    u32* xbf    = (u32*)alloc((size_t)N_NODES * 64 * 4);
    u32* agg    = (u32*)alloc((size_t)N_NODES * 64 * 4);
    u32* h2a    = (u32*)alloc((size_t)N_NODES * 64 * 4);
    u32* h2b    = (u32*)alloc((size_t)N_NODES * 64 * 4);
    short* W1t  = (short*)alloc((size_t)NLAYER * 128 * 128 * 2);
    short* W2t  = (short*)alloc((size_t)NLAYER * 128 * 128 * 2);
    float* sumsL = (float*)alloc(NLAYER * 256 * 4);
    float* gsumL = (float*)alloc((size_t)NLAYER * NGRAPH * 128 * 4);
    size_t zero2_len = (char*)gsumL - (char*)sumsL + (size_t)NLAYER * NGRAPH * 128 * 4;
    float* coefL = (float*)alloc(NLAYER * 256 * 4);

    hipMemsetAsync(deg, 0, zero1_len, stream);
    hipMemsetAsync(sumsL, 0, zero2_len, stream);

    cvt_x<<<(N_NODES * 64 + 255) / 256, 256, 0, stream>>>((const float2*)x0, xbf);
    {
        dim3 gw(128, NLAYER, 2);
        cvt_w<<<gw, 128, 0, stream>>>(W1, W2, W1t, W2t);
    }
    count_deg<<<(N_EDGES + 255) / 256, 256, 0, stream>>>(dst, deg);
    scan_l1<<<SCAN_NB, 256, 0, stream>>>(deg, bscan, bsum);
    scan_l2<<<1, 256, 0, stream>>>(bsum, boff);
    scan_l3<<<SCAN_NB, 256, 0, stream>>>(bscan, boff, rowp);
    fill_csr<<<(N_EDGES + 255) / 256, 256, 0, stream>>>(src, dst, rowp, cursor, col);

    const u32* xin = xbf;
    for (int l = 0; l < NLAYER; ++l) {
        u32* h2 = (l & 1) ? h2b : h2a;
        const float* coef_prev = (l == 0) ? nullptr : (coefL + (l - 1) * 256);
        agg_kernel<<<(N_NODES + 3) / 4, 256, 0, stream>>>(
            xin, coef_prev, rowp, col, eps, l, agg);
        mlp_fused<<<(N_NODES + 127) / 128, 256, 0, stream>>>(
            (const short*)agg, W1t + (size_t)l * 16384, b1 + l * 128,
            W2t + (size_t)l * 16384, b2 + l * 128, (short*)h2, N_NODES);
        stats_pool<<<(N_NODES + 127) / 128, 128, 0, stream>>>(
            (const u32*)h2, batch, sumsL + l * 256, gsumL + (size_t)l * NGRAPH * 128);
        bn_finalize<<<1, 128, 0, stream>>>(sumsL + l * 256, gamma, beta, l,
                                           coefL + l * 256);
        xin = h2;
    }
    head_kernel<<<NGRAPH, 256, 0, stream>>>(gsumL, coefL, batch, emb,
                                            l1w, l1b, l2w, l2b, l4w, l4b,
                                            (float*)d_out);
}

// Round 6
// 586.854 us; speedup vs baseline: 2.0408x; 1.1211x over previous
//
#include <hip/hip_runtime.h>
#include <cstdint>
#include <cstddef>

#define N_NODES 50000
#define N_EDGES 600000
#define NLAYER  4
#define NGRAPH  64
#define SCAN_NB 196   // ceil(50000/256)

typedef unsigned int   u32;
typedef unsigned short u16;
typedef float f32x4  __attribute__((ext_vector_type(4)));
typedef short bf16x8 __attribute__((ext_vector_type(8)));

// ---------- bf16 helpers ----------
__device__ __forceinline__ float bf1(u16 u)  { return __uint_as_float(((u32)u) << 16); }
__device__ __forceinline__ float bflo(u32 u) { return __uint_as_float(u << 16); }
__device__ __forceinline__ float bfhi(u32 u) { return __uint_as_float(u & 0xffff0000u); }
__device__ __forceinline__ u16 f2bf(float f) {
    u32 x = __float_as_uint(f);
    u32 r = x + 0x7fffu + ((x >> 16) & 1u);   // RNE
    return (u16)(r >> 16);
}
__device__ __forceinline__ u32 pack2(float a, float b) {
    return (u32)f2bf(a) | ((u32)f2bf(b) << 16);
}

// ---------- dtype conversion ----------
__global__ __launch_bounds__(256) void cvt_x(const float2* __restrict__ x,
                                             u32* __restrict__ xbf) {
    int i = blockIdx.x * 256 + threadIdx.x;
    if (i < N_NODES * 64) { float2 v = x[i]; xbf[i] = pack2(v.x, v.y); }
}

// W: [L][128 k][128 n] fp32 -> Wt: [L][128 n][128 k] bf16; z selects W1/W2
__global__ __launch_bounds__(128) void cvt_w(const float* __restrict__ W1,
                                             const float* __restrict__ W2,
                                             short* __restrict__ W1t,
                                             short* __restrict__ W2t) {
    int l = blockIdx.y, n = blockIdx.x, k = threadIdx.x;
    const float* W = blockIdx.z ? W2 : W1;
    short* Wt      = blockIdx.z ? W2t : W1t;
    Wt[((size_t)l * 128 + n) * 128 + k] = (short)f2bf(W[((size_t)l * 128 + k) * 128 + n]);
}

// ---------- CSR build ----------
__global__ void count_deg(const int* __restrict__ dst, int* __restrict__ deg) {
    int e = blockIdx.x * 256 + threadIdx.x;
    if (e < N_EDGES) atomicAdd(&deg[dst[e]], 1);
}

__global__ __launch_bounds__(256) void scan_l1(const int* __restrict__ deg,
                                               int* __restrict__ bscan,
                                               int* __restrict__ bsum) {
    __shared__ int sd[256];
    int tid = threadIdx.x;
    int i = blockIdx.x * 256 + tid;
    int v = (i < N_NODES) ? deg[i] : 0;
    sd[tid] = v; __syncthreads();
#pragma unroll
    for (int off = 1; off < 256; off <<= 1) {
        int t = (tid >= off) ? sd[tid - off] : 0;
        __syncthreads();
        sd[tid] += t; __syncthreads();
    }
    if (i < N_NODES) bscan[i] = sd[tid];
    if (tid == 255) bsum[blockIdx.x] = sd[255];
}

__global__ __launch_bounds__(256) void scan_l2(const int* __restrict__ bsum,
                                               int* __restrict__ boff) {
    __shared__ int sd[256];
    int tid = threadIdx.x;
    int v = (tid < SCAN_NB) ? bsum[tid] : 0;
    sd[tid] = v; __syncthreads();
#pragma unroll
    for (int off = 1; off < 256; off <<= 1) {
        int t = (tid >= off) ? sd[tid - off] : 0;
        __syncthreads();
        sd[tid] += t; __syncthreads();
    }
    if (tid < SCAN_NB) boff[tid] = sd[tid] - v;
}

__global__ __launch_bounds__(256) void scan_l3(const int* __restrict__ bscan,
                                               const int* __restrict__ boff,
                                               int* __restrict__ rowp) {
    int i = blockIdx.x * 256 + threadIdx.x;
    if (i == 0) rowp[0] = 0;
    if (i < N_NODES) rowp[i + 1] = bscan[i] + boff[blockIdx.x];
}

__global__ void fill_csr(const int* __restrict__ src, const int* __restrict__ dst,
                         const int* __restrict__ rowp, int* __restrict__ cursor,
                         int* __restrict__ col) {
    int e = blockIdx.x * 256 + threadIdx.x;
    if (e < N_EDGES) {
        int d = dst[e];
        int pos = atomicAdd(&cursor[d], 1);
        col[rowp[d] + pos] = src[e];
    }
}

// ---------- GIN aggregation (bf16, fp32 accum, analytic BN of prev layer) ----------
// agg[i] = (1+eps)*(a*x_i+d) + a*sum_j x_j + deg_i*d
// one wave per node; 8-wide software-pipelined edge loop, mask-padded tail
__global__ __launch_bounds__(256) void agg_kernel(
    const u32* __restrict__ xin, const float* __restrict__ coef,
    const int* __restrict__ rowp, const int* __restrict__ col,
    const float* __restrict__ eps_all, int layer,
    u32* __restrict__ agg) {
    int node = blockIdx.x * 4 + (threadIdx.x >> 6);
    int lane = threadIdx.x & 63;
    if (node >= N_NODES) return;
    float a0 = 1.f, a1 = 1.f, d0 = 0.f, d1 = 0.f;
    if (coef) {
        a0 = coef[2 * lane];       a1 = coef[2 * lane + 1];
        d0 = coef[128 + 2 * lane]; d1 = coef[128 + 2 * lane + 1];
    }
    float ep = 1.0f + eps_all[layer];
    u32 v = xin[(size_t)node * 64 + lane];
    int k0 = rowp[node], k1 = rowp[node + 1];
    float s0 = 0.f, s1 = 0.f;
    int k = k0;
    int cc[8];
    if (k < k1) {
#pragma unroll
        for (int t = 0; t < 8; t++) cc[t] = col[min(k + t, k1 - 1)];
    }
    while (k < k1) {
        int idx[8];
#pragma unroll
        for (int t = 0; t < 8; t++) idx[t] = cc[t];
        int kn = k + 8;
        if (kn < k1) {
#pragma unroll
            for (int t = 0; t < 8; t++) cc[t] = col[min(kn + t, k1 - 1)];
        }
#pragma unroll
        for (int t = 0; t < 8; t++) {
            u32 u = xin[(size_t)idx[t] * 64 + lane];
            float w = (k + t < k1) ? 1.f : 0.f;
            s0 += w * bflo(u); s1 += w * bfhi(u);
        }
        k = kn;
    }
    float deg = (float)(k1 - k0);
    float r0 = ep * (a0 * bflo(v) + d0) + a0 * s0 + deg * d0;
    float r1 = ep * (a1 * bfhi(v) + d1) + a1 * s1 + deg * d1;
    agg[(size_t)node * 64 + lane] = pack2(r0, r1);
}

// ---------- fused MLP: h2 = relu(relu(A@W1+b1)@W2+b2), bf16 MFMA, h1 in LDS ----------
#define H1_STRIDE 136
__global__ __launch_bounds__(256) void mlp_fused(
    const short* __restrict__ A,
    const short* __restrict__ W1t, const float* __restrict__ b1,
    const short* __restrict__ W2t, const float* __restrict__ b2,
    short* __restrict__ H2, int M) {
    __shared__ short h1s[128 * H1_STRIDE];
    int tid  = threadIdx.x;
    int wave = tid >> 6, lane = tid & 63;
    int ln15 = lane & 15, quad = lane >> 4;
    int m0 = blockIdx.x * 128 + wave * 32;
    const bf16x8 zz = {0, 0, 0, 0, 0, 0, 0, 0};

    bf16x8 a[2][4];
#pragma unroll
    for (int rt = 0; rt < 2; rt++) {
        int row = m0 + rt * 16 + ln15;
        const short* rp = A + (size_t)row * 128 + quad * 8;
        bool ok = row < M;
#pragma unroll
        for (int s = 0; s < 4; s++)
            a[rt][s] = ok ? *(const bf16x8*)(rp + s * 32) : zz;
    }
#pragma unroll
    for (int ct = 0; ct < 8; ct++) {
        const short* wp = W1t + (size_t)(ct * 16 + ln15) * 128 + quad * 8;
        bf16x8 b[4];
#pragma unroll
        for (int s = 0; s < 4; s++) b[s] = *(const bf16x8*)(wp + s * 32);
        float bias = b1[ct * 16 + ln15];
#pragma unroll
        for (int rt = 0; rt < 2; rt++) {
            f32x4 acc = {0.f, 0.f, 0.f, 0.f};
#pragma unroll
            for (int s = 0; s < 4; s++)
                acc = __builtin_amdgcn_mfma_f32_16x16x32_bf16(a[rt][s], b[s], acc, 0, 0, 0);
#pragma unroll
            for (int i = 0; i < 4; i++) {
                float v = fmaxf(acc[i] + bias, 0.f);
                int lr = wave * 32 + rt * 16 + quad * 4 + i;
                h1s[lr * H1_STRIDE + ct * 16 + ln15] = (short)f2bf(v);
            }
        }
    }
    __syncthreads();
    bf16x8 c[2][4];
#pragma unroll
    for (int rt = 0; rt < 2; rt++) {
        const short* rp = h1s + (size_t)(wave * 32 + rt * 16 + ln15) * H1_STRIDE + quad * 8;
#pragma unroll
        for (int s = 0; s < 4; s++) c[rt][s] = *(const bf16x8*)(rp + s * 32);
    }
#pragma unroll
    for (int ct = 0; ct < 8; ct++) {
        const short* wp = W2t + (size_t)(ct * 16 + ln15) * 128 + quad * 8;
        bf16x8 b[4];
#pragma unroll
        for (int s = 0; s < 4; s++) b[s] = *(const bf16x8*)(wp + s * 32);
        float bias = b2[ct * 16 + ln15];
#pragma unroll
        for (int rt = 0; rt < 2; rt++) {
            f32x4 acc = {0.f, 0.f, 0.f, 0.f};
#pragma unroll
            for (int s = 0; s < 4; s++)
                acc = __builtin_amdgcn_mfma_f32_16x16x32_bf16(c[rt][s], b[s], acc, 0, 0, 0);
            int colx = ct * 16 + ln15;
#pragma unroll
            for (int i = 0; i < 4; i++) {
                int row = m0 + rt * 16 + quad * 4 + i;
                if (row < M) {
                    float v = fmaxf(acc[i] + bias, 0.f);
                    H2[(size_t)row * 128 + colx] = (short)f2bf(v);
                }
            }
        }
    }
}

// ---------- BN stats + per-graph sums: 4 waves/block, 16 rows/wave, 4-wide loads ----------
__global__ __launch_bounds__(256) void stats_pool(
    const u32* __restrict__ h2, const int* __restrict__ batch,
    float* __restrict__ sums /*[256]*/, float* __restrict__ gsum /*[G*128]*/) {
    int lane = threadIdx.x & 63;
    int wave = threadIdx.x >> 6;
    int r0 = blockIdx.x * 64 + wave * 16;
    float s0 = 0.f, s1 = 0.f, q0 = 0.f, q1 = 0.f;
    if (r0 < N_NODES) {
        int r1 = min(r0 + 16, N_NODES);
        float p0 = 0.f, p1 = 0.f;
        int curg = batch[r0];
        int r = r0;
        while (r < r1) {
            int nb = min(4, r1 - r);
            u32 u[4]; int gg[4];
#pragma unroll
            for (int t = 0; t < 4; t++) {
                if (t < nb) { u[t] = h2[(size_t)(r + t) * 64 + lane]; gg[t] = batch[r + t]; }
            }
#pragma unroll
            for (int t = 0; t < 4; t++) {
                if (t < nb) {
                    if (gg[t] != curg) {   // wave-uniform branch
                        atomicAdd(&gsum[curg * 128 + 2 * lane],     p0);
                        atomicAdd(&gsum[curg * 128 + 2 * lane + 1], p1);
                        p0 = p1 = 0.f; curg = gg[t];
                    }
                    float a = bflo(u[t]), b = bfhi(u[t]);
                    s0 += a; s1 += b; q0 += a * a; q1 += b * b;
                    p0 += a; p1 += b;
                }
            }
            r += nb;
        }
        atomicAdd(&gsum[curg * 128 + 2 * lane],     p0);
        atomicAdd(&gsum[curg * 128 + 2 * lane + 1], p1);
    }
    // block-wide reduction of column sums before hitting the 256 hot cells
    __shared__ float red[4][256];
    red[wave][lane]       = s0;
    red[wave][64 + lane]  = s1;
    red[wave][128 + lane] = q0;
    red[wave][192 + lane] = q1;
    __syncthreads();
    int t = threadIdx.x;
    float v = red[0][t] + red[1][t] + red[2][t] + red[3][t];
    int part = t >> 6, ln = t & 63;
    int target = (part == 0) ? (2 * ln) : (part == 1) ? (2 * ln + 1)
               : (part == 2) ? (128 + 2 * ln) : (128 + 2 * ln + 1);
    atomicAdd(&sums[target], v);
}

__global__ void bn_finalize(const float* __restrict__ sums,
                            const float* __restrict__ gamma, const float* __restrict__ beta,
                            int layer, float* __restrict__ coef) {
    int c = threadIdx.x;  // 128
    float mean = sums[c] / (float)N_NODES;
    float var  = sums[128 + c] / (float)N_NODES - mean * mean;
    float istd = rsqrtf(var + 1e-5f);
    float a = istd * gamma[layer * 128 + c];
    coef[c]       = a;
    coef[128 + c] = beta[layer * 128 + c] - mean * a;
}

// ---------- head ----------
__global__ __launch_bounds__(256) void head_kernel(
    const float* __restrict__ gsum, const float* __restrict__ coefL,
    const int* __restrict__ batch, const float* __restrict__ emb,
    const float* __restrict__ l1w, const float* __restrict__ l1b,
    const float* __restrict__ l2w, const float* __restrict__ l2b,
    const float* __restrict__ l4w, const float* __restrict__ l4b,
    float* __restrict__ out) {
    __shared__ float z[576];
    __shared__ float z1[256];
    __shared__ float z2[128];
    __shared__ float z3s[10];
    __shared__ float inv_cnt;
    int g = blockIdx.x;
    int tid = threadIdx.x;
    if (tid == 0) {
        int lo = 0, hi = N_NODES;
        while (lo < hi) { int m = (lo + hi) >> 1; if (batch[m] < g) lo = m + 1; else hi = m; }
        int s = lo;
        lo = 0; hi = N_NODES;
        while (lo < hi) { int m = (lo + hi) >> 1; if (batch[m] < g + 1) lo = m + 1; else hi = m; }
        inv_cnt = 1.0f / fmaxf((float)(lo - s), 1.0f);
    }
    __syncthreads();
    for (int j = tid; j < 512; j += 256) {
        int l = j >> 7, c = j & 127;
        float a = coefL[l * 256 + c], d = coefL[l * 256 + 128 + c];
        z[j] = a * gsum[(size_t)l * NGRAPH * 128 + g * 128 + c] * inv_cnt + d;
    }
    if (tid < 64) z[512 + tid] = emb[g * 64 + tid];
    __syncthreads();
    {
        float acc = l1b[tid];
        for (int j = 0; j < 576; j++) acc += z[j] * l1w[j * 256 + tid];
        z1[tid] = fmaxf(acc, 0.f);
    }
    __syncthreads();
    if (tid < 128) {
        float acc = l2b[tid];
        for (int j = 0; j < 256; j++) acc += z1[j] * l2w[j * 128 + tid];
        z2[tid] = fmaxf(acc, 0.f);
    }
    __syncthreads();
    if (tid < 10) {
        float acc = l4b[tid];
        for (int j = 0; j < 128; j++) acc += z2[j] * l4w[j * 10 + tid];
        z3s[tid] = acc;
    }
    __syncthreads();
    if (tid == 0) {
        float m = z3s[0];
        for (int i = 1; i < 10; i++) m = fmaxf(m, z3s[i]);
        float se = 0.f;
        for (int i = 0; i < 10; i++) se += expf(z3s[i] - m);
        float lse = m + logf(se);
        for (int i = 0; i < 10; i++) out[g * 10 + i] = z3s[i] - lse;
    }
}

extern "C" void kernel_launch(void* const* d_in, const int* in_sizes, int n_in,
                              void* d_out, int out_size, void* d_ws, size_t ws_size,
                              hipStream_t stream) {
    (void)in_sizes; (void)n_in; (void)out_size; (void)ws_size;
    const float* x0   = (const float*)d_in[0];
    const int* ei     = (const int*)d_in[1];
    const int* src    = ei;
    const int* dst    = ei + N_EDGES;
    const int* batch  = (const int*)d_in[2];
    const float* emb  = (const float*)d_in[3];
    const float* eps  = (const float*)d_in[4];
    const float* W1   = (const float*)d_in[5];
    const float* b1   = (const float*)d_in[6];
    const float* W2   = (const float*)d_in[7];
    const float* b2   = (const float*)d_in[8];
    const float* gamma= (const float*)d_in[9];
    const float* beta = (const float*)d_in[10];
    const float* l1w  = (const float*)d_in[11];
    const float* l1b  = (const float*)d_in[12];
    const float* l2w  = (const float*)d_in[13];
    const float* l2b  = (const float*)d_in[14];
    const float* l4w  = (const float*)d_in[15];
    const float* l4b  = (const float*)d_in[16];

    char* ws = (char*)d_ws;
    size_t off = 0;
    auto alloc = [&](size_t bytes) -> char* {
        char* p = ws + off; off += (bytes + 255) & ~(size_t)255; return p;
    };
    int* deg    = (int*)alloc(N_NODES * 4);
    int* cursor = (int*)alloc(N_NODES * 4);
    size_t zero1_len = (char*)cursor - (char*)deg + (((size_t)N_NODES * 4 + 255) & ~(size_t)255);
    int* rowp   = (int*)alloc((N_NODES + 1) * 4);
    int* bscan  = (int*)alloc(N_NODES * 4);
    int* bsum   = (int*)alloc(SCAN_NB * 4);
    int* boff   = (int*)alloc(SCAN_NB * 4);
    int* col    = (int*)alloc(N_EDGES * 4);
    u32* xbf    = (u32*)alloc((size_t)N_NODES * 64 * 4);
    u32* agg    = (u32*)alloc((size_t)N_NODES * 64 * 4);
    u32* h2a    = (u32*)alloc((size_t)N_NODES * 64 * 4);
    u32* h2b    = (u32*)alloc((size_t)N_NODES * 64 * 4);
    short* W1t  = (short*)alloc((size_t)NLAYER * 128 * 128 * 2);
    short* W2t  = (short*)alloc((size_t)NLAYER * 128 * 128 * 2);
    float* sumsL = (float*)alloc(NLAYER * 256 * 4);
    float* gsumL = (float*)alloc((size_t)NLAYER * NGRAPH * 128 * 4);
    size_t zero2_len = (char*)gsumL - (char*)sumsL + (size_t)NLAYER * NGRAPH * 128 * 4;
    float* coefL = (float*)alloc(NLAYER * 256 * 4);

    hipMemsetAsync(deg, 0, zero1_len, stream);
    hipMemsetAsync(sumsL, 0, zero2_len, stream);

    cvt_x<<<(N_NODES * 64 + 255) / 256, 256, 0, stream>>>((const float2*)x0, xbf);
    {
        dim3 gw(128, NLAYER, 2);
        cvt_w<<<gw, 128, 0, stream>>>(W1, W2, W1t, W2t);
    }
    count_deg<<<(N_EDGES + 255) / 256, 256, 0, stream>>>(dst, deg);
    scan_l1<<<SCAN_NB, 256, 0, stream>>>(deg, bscan, bsum);
    scan_l2<<<1, 256, 0, stream>>>(bsum, boff);
    scan_l3<<<SCAN_NB, 256, 0, stream>>>(bscan, boff, rowp);
    fill_csr<<<(N_EDGES + 255) / 256, 256, 0, stream>>>(src, dst, rowp, cursor, col);

    const u32* xin = xbf;
    for (int l = 0; l < NLAYER; ++l) {
        u32* h2 = (l & 1) ? h2b : h2a;
        const float* coef_prev = (l == 0) ? nullptr : (coefL + (l - 1) * 256);
        agg_kernel<<<(N_NODES + 3) / 4, 256, 0, stream>>>(
            xin, coef_prev, rowp, col, eps, l, agg);
        mlp_fused<<<(N_NODES + 127) / 128, 256, 0, stream>>>(
            (const short*)agg, W1t + (size_t)l * 16384, b1 + l * 128,
            W2t + (size_t)l * 16384, b2 + l * 128, (short*)h2, N_NODES);
        stats_pool<<<(N_NODES + 63) / 64, 256, 0, stream>>>(
            (const u32*)h2, batch, sumsL + l * 256, gsumL + (size_t)l * NGRAPH * 128);
        bn_finalize<<<1, 128, 0, stream>>>(sumsL + l * 256, gamma, beta, l,
                                           coefL + l * 256);
        xin = h2;
    }
    head_kernel<<<NGRAPH, 256, 0, stream>>>(gsumL, coefL, batch, emb,
                                            l1w, l1b, l2w, l2b, l4w, l4b,
                                            (float*)d_out);
}

// Round 7
// 424.813 us; speedup vs baseline: 2.8193x; 1.3814x over previous
//
#include <hip/hip_runtime.h>
#include <cstdint>
#include <cstddef>

#define N_NODES 50000
#define N_EDGES 600000
#define NLAYER  4
#define NGRAPH  64
#define SCAN_NB 196   // ceil(50000/256)
#define NBLK_MLP ((N_NODES + 127) / 128)   // 391

typedef unsigned int   u32;
typedef unsigned short u16;
typedef float f32x4  __attribute__((ext_vector_type(4)));
typedef short bf16x8 __attribute__((ext_vector_type(8)));

// ---------- bf16 helpers ----------
__device__ __forceinline__ float bf1(u16 u)  { return __uint_as_float(((u32)u) << 16); }
__device__ __forceinline__ float bflo(u32 u) { return __uint_as_float(u << 16); }
__device__ __forceinline__ float bfhi(u32 u) { return __uint_as_float(u & 0xffff0000u); }
__device__ __forceinline__ u16 f2bf(float f) {
    u32 x = __float_as_uint(f);
    u32 r = x + 0x7fffu + ((x >> 16) & 1u);   // RNE
    return (u16)(r >> 16);
}
__device__ __forceinline__ u32 pack2(float a, float b) {
    return (u32)f2bf(a) | ((u32)f2bf(b) << 16);
}

// ---------- dtype conversion ----------
__global__ __launch_bounds__(256) void cvt_x(const float2* __restrict__ x,
                                             u32* __restrict__ xbf) {
    int i = blockIdx.x * 256 + threadIdx.x;
    if (i < N_NODES * 64) { float2 v = x[i]; xbf[i] = pack2(v.x, v.y); }
}

// W: [L][128 k][128 n] fp32 -> Wt: [L][128 n][128 k] bf16; z selects W1/W2
__global__ __launch_bounds__(128) void cvt_w(const float* __restrict__ W1,
                                             const float* __restrict__ W2,
                                             short* __restrict__ W1t,
                                             short* __restrict__ W2t) {
    int l = blockIdx.y, n = blockIdx.x, k = threadIdx.x;
    const float* W = blockIdx.z ? W2 : W1;
    short* Wt      = blockIdx.z ? W2t : W1t;
    Wt[((size_t)l * 128 + n) * 128 + k] = (short)f2bf(W[((size_t)l * 128 + k) * 128 + n]);
}

// ---------- CSR build ----------
__global__ void count_deg(const int* __restrict__ dst, int* __restrict__ deg) {
    int e = blockIdx.x * 256 + threadIdx.x;
    if (e < N_EDGES) atomicAdd(&deg[dst[e]], 1);
}

__global__ __launch_bounds__(256) void scan_l1(const int* __restrict__ deg,
                                               int* __restrict__ bscan,
                                               int* __restrict__ bsum) {
    __shared__ int sd[256];
    int tid = threadIdx.x;
    int i = blockIdx.x * 256 + tid;
    int v = (i < N_NODES) ? deg[i] : 0;
    sd[tid] = v; __syncthreads();
#pragma unroll
    for (int off = 1; off < 256; off <<= 1) {
        int t = (tid >= off) ? sd[tid - off] : 0;
        __syncthreads();
        sd[tid] += t; __syncthreads();
    }
    if (i < N_NODES) bscan[i] = sd[tid];
    if (tid == 255) bsum[blockIdx.x] = sd[255];
}

__global__ __launch_bounds__(256) void scan_l2(const int* __restrict__ bsum,
                                               int* __restrict__ boff) {
    __shared__ int sd[256];
    int tid = threadIdx.x;
    int v = (tid < SCAN_NB) ? bsum[tid] : 0;
    sd[tid] = v; __syncthreads();
#pragma unroll
    for (int off = 1; off < 256; off <<= 1) {
        int t = (tid >= off) ? sd[tid - off] : 0;
        __syncthreads();
        sd[tid] += t; __syncthreads();
    }
    if (tid < SCAN_NB) boff[tid] = sd[tid] - v;
}

__global__ __launch_bounds__(256) void scan_l3(const int* __restrict__ bscan,
                                               const int* __restrict__ boff,
                                               int* __restrict__ rowp) {
    int i = blockIdx.x * 256 + threadIdx.x;
    if (i == 0) rowp[0] = 0;
    if (i < N_NODES) rowp[i + 1] = bscan[i] + boff[blockIdx.x];
}

__global__ void fill_csr(const int* __restrict__ src, const int* __restrict__ dst,
                         const int* __restrict__ rowp, int* __restrict__ cursor,
                         int* __restrict__ col) {
    int e = blockIdx.x * 256 + threadIdx.x;
    if (e < N_EDGES) {
        int d = dst[e];
        int pos = atomicAdd(&cursor[d], 1);
        col[rowp[d] + pos] = src[e];
    }
}

// ---------- GIN aggregation (bf16, fp32 accum, analytic BN of prev layer) ----------
__global__ __launch_bounds__(256) void agg_kernel(
    const u32* __restrict__ xin, const float* __restrict__ coef,
    const int* __restrict__ rowp, const int* __restrict__ col,
    const float* __restrict__ eps_all, int layer,
    u32* __restrict__ agg) {
    int node = blockIdx.x * 4 + (threadIdx.x >> 6);
    int lane = threadIdx.x & 63;
    if (node >= N_NODES) return;
    float a0 = 1.f, a1 = 1.f, d0 = 0.f, d1 = 0.f;
    if (coef) {
        a0 = coef[2 * lane];       a1 = coef[2 * lane + 1];
        d0 = coef[128 + 2 * lane]; d1 = coef[128 + 2 * lane + 1];
    }
    float ep = 1.0f + eps_all[layer];
    u32 v = xin[(size_t)node * 64 + lane];
    int k0 = rowp[node], k1 = rowp[node + 1];
    float s0 = 0.f, s1 = 0.f;
    int k = k0;
    int cc[8];
    if (k < k1) {
#pragma unroll
        for (int t = 0; t < 8; t++) cc[t] = col[min(k + t, k1 - 1)];
    }
    while (k < k1) {
        int idx[8];
#pragma unroll
        for (int t = 0; t < 8; t++) idx[t] = cc[t];
        int kn = k + 8;
        if (kn < k1) {
#pragma unroll
            for (int t = 0; t < 8; t++) cc[t] = col[min(kn + t, k1 - 1)];
        }
#pragma unroll
        for (int t = 0; t < 8; t++) {
            u32 u = xin[(size_t)idx[t] * 64 + lane];
            float w = (k + t < k1) ? 1.f : 0.f;
            s0 += w * bflo(u); s1 += w * bfhi(u);
        }
        k = kn;
    }
    float deg = (float)(k1 - k0);
    float r0 = ep * (a0 * bflo(v) + d0) + a0 * s0 + deg * d0;
    float r1 = ep * (a1 * bfhi(v) + d1) + a1 * s1 + deg * d1;
    agg[(size_t)node * 64 + lane] = pack2(r0, r1);
}

// ---------- fused MLP + BN-stats + per-graph pooling ----------
// h2 = relu(relu(A@W1+b1)@W2+b2); column sum/sumsq -> partial[blk][256] (non-atomic);
// per-graph pooled column sums -> gsum atomics (block spans <= 2 graphs; pB = s - pA).
#define H1_STRIDE 136
__global__ __launch_bounds__(256) void mlp_fused(
    const short* __restrict__ A,
    const short* __restrict__ W1t, const float* __restrict__ b1,
    const short* __restrict__ W2t, const float* __restrict__ b2,
    short* __restrict__ H2, const int* __restrict__ batch,
    float* __restrict__ partial, float* __restrict__ gsum, int M) {
    __shared__ alignas(16) short h1s[128 * H1_STRIDE];   // 34816 B, reused as scratch
    __shared__ int sh_ga, sh_gb, sh_split;
    int tid  = threadIdx.x;
    int wave = tid >> 6, lane = tid & 63;
    int ln15 = lane & 15, quad = lane >> 4;
    int m0blk = blockIdx.x * 128;
    int m0 = m0blk + wave * 32;
    const bf16x8 zz = {0, 0, 0, 0, 0, 0, 0, 0};

    if (tid == 0) {   // graph segmentation of this block's rows (batch sorted)
        int rlo = m0blk, rhi = min(m0blk + 127, M - 1);
        int ga = batch[rlo], gb = batch[rhi];
        int split = m0blk + 128;
        if (ga != gb) {
            int lo = rlo, hi = rhi;   // batch[lo]==ga, batch[hi]!=ga
            while (lo + 1 < hi) { int mid = (lo + hi) >> 1; if (batch[mid] == ga) lo = mid; else hi = mid; }
            split = hi;
        }
        sh_ga = ga; sh_gb = gb; sh_split = split;
    }

    bf16x8 a[2][4];
#pragma unroll
    for (int rt = 0; rt < 2; rt++) {
        int row = m0 + rt * 16 + ln15;
        const short* rp = A + (size_t)row * 128 + quad * 8;
        bool ok = row < M;
#pragma unroll
        for (int s = 0; s < 4; s++)
            a[rt][s] = ok ? *(const bf16x8*)(rp + s * 32) : zz;
    }
#pragma unroll
    for (int ct = 0; ct < 8; ct++) {
        const short* wp = W1t + (size_t)(ct * 16 + ln15) * 128 + quad * 8;
        bf16x8 b[4];
#pragma unroll
        for (int s = 0; s < 4; s++) b[s] = *(const bf16x8*)(wp + s * 32);
        float bias = b1[ct * 16 + ln15];
#pragma unroll
        for (int rt = 0; rt < 2; rt++) {
            f32x4 acc = {0.f, 0.f, 0.f, 0.f};
#pragma unroll
            for (int s = 0; s < 4; s++)
                acc = __builtin_amdgcn_mfma_f32_16x16x32_bf16(a[rt][s], b[s], acc, 0, 0, 0);
#pragma unroll
            for (int i = 0; i < 4; i++) {
                float v = fmaxf(acc[i] + bias, 0.f);
                int lr = wave * 32 + rt * 16 + quad * 4 + i;
                h1s[lr * H1_STRIDE + ct * 16 + ln15] = (short)f2bf(v);
            }
        }
    }
    __syncthreads();
    bf16x8 c[2][4];
#pragma unroll
    for (int rt = 0; rt < 2; rt++) {
        const short* rp = h1s + (size_t)(wave * 32 + rt * 16 + ln15) * H1_STRIDE + quad * 8;
#pragma unroll
        for (int s = 0; s < 4; s++) c[rt][s] = *(const bf16x8*)(rp + s * 32);
    }
    int gsplit = sh_split;
    float sAcc[8], qAcc[8], pAcc[8];
#pragma unroll
    for (int ct = 0; ct < 8; ct++) { sAcc[ct] = 0.f; qAcc[ct] = 0.f; pAcc[ct] = 0.f; }
#pragma unroll
    for (int ct = 0; ct < 8; ct++) {
        const short* wp = W2t + (size_t)(ct * 16 + ln15) * 128 + quad * 8;
        bf16x8 b[4];
#pragma unroll
        for (int s = 0; s < 4; s++) b[s] = *(const bf16x8*)(wp + s * 32);
        float bias = b2[ct * 16 + ln15];
#pragma unroll
        for (int rt = 0; rt < 2; rt++) {
            f32x4 acc = {0.f, 0.f, 0.f, 0.f};
#pragma unroll
            for (int s = 0; s < 4; s++)
                acc = __builtin_amdgcn_mfma_f32_16x16x32_bf16(c[rt][s], b[s], acc, 0, 0, 0);
            int colx = ct * 16 + ln15;
#pragma unroll
            for (int i = 0; i < 4; i++) {
                int row = m0 + rt * 16 + quad * 4 + i;
                float v = fmaxf(acc[i] + bias, 0.f);
                if (row < M) H2[(size_t)row * 128 + colx] = (short)f2bf(v);
                float vm = (row < M) ? v : 0.f;
                sAcc[ct] += vm; qAcc[ct] += vm * vm;
                if (row < gsplit) pAcc[ct] += vm;
            }
        }
    }
    __syncthreads();   // all h1s reads done -> reuse as float scratch
    float* scr = (float*)h1s;          // [3][16 slices][128 cols] = 24576 B
    int slice = wave * 4 + quad;
#pragma unroll
    for (int ct = 0; ct < 8; ct++) {
        int colx = ct * 16 + ln15;
        scr[(0 * 16 + slice) * 128 + colx] = sAcc[ct];
        scr[(1 * 16 + slice) * 128 + colx] = qAcc[ct];
        scr[(2 * 16 + slice) * 128 + colx] = pAcc[ct];
    }
    __syncthreads();
    if (tid < 128) {
        float ss = 0.f, qq = 0.f, pa = 0.f;
#pragma unroll
        for (int sl = 0; sl < 16; sl++) {
            ss += scr[(0 * 16 + sl) * 128 + tid];
            qq += scr[(1 * 16 + sl) * 128 + tid];
            pa += scr[(2 * 16 + sl) * 128 + tid];
        }
        partial[(size_t)blockIdx.x * 256 + tid]       = ss;
        partial[(size_t)blockIdx.x * 256 + 128 + tid] = qq;
        int ga = sh_ga, gb = sh_gb;
        atomicAdd(&gsum[ga * 128 + tid], pa);
        if (gb != ga) atomicAdd(&gsum[gb * 128 + tid], ss - pa);
    }
}

// ---------- fold block partials into sums (31 atomic hits per cell) ----------
__global__ __launch_bounds__(256) void reduce_partials(
    const float* __restrict__ partial, float* __restrict__ sums) {
    int t = threadIdx.x;
    int b0 = blockIdx.x * 13, b1 = min(b0 + 13, NBLK_MLP);
    if (b0 >= NBLK_MLP) return;
    float acc = 0.f;
    for (int b = b0; b < b1; b++) acc += partial[(size_t)b * 256 + t];
    atomicAdd(&sums[t], acc);
}

__global__ void bn_finalize(const float* __restrict__ sums,
                            const float* __restrict__ gamma, const float* __restrict__ beta,
                            int layer, float* __restrict__ coef) {
    int c = threadIdx.x;  // 128
    float mean = sums[c] / (float)N_NODES;
    float var  = sums[128 + c] / (float)N_NODES - mean * mean;
    float istd = rsqrtf(var + 1e-5f);
    float a = istd * gamma[layer * 128 + c];
    coef[c]       = a;
    coef[128 + c] = beta[layer * 128 + c] - mean * a;
}

// ---------- head ----------
__global__ __launch_bounds__(256) void head_kernel(
    const float* __restrict__ gsum, const float* __restrict__ coefL,
    const int* __restrict__ batch, const float* __restrict__ emb,
    const float* __restrict__ l1w, const float* __restrict__ l1b,
    const float* __restrict__ l2w, const float* __restrict__ l2b,
    const float* __restrict__ l4w, const float* __restrict__ l4b,
    float* __restrict__ out) {
    __shared__ float z[576];
    __shared__ float z1[256];
    __shared__ float z2[128];
    __shared__ float z3s[10];
    __shared__ float inv_cnt;
    int g = blockIdx.x;
    int tid = threadIdx.x;
    if (tid == 0) {
        int lo = 0, hi = N_NODES;
        while (lo < hi) { int m = (lo + hi) >> 1; if (batch[m] < g) lo = m + 1; else hi = m; }
        int s = lo;
        lo = 0; hi = N_NODES;
        while (lo < hi) { int m = (lo + hi) >> 1; if (batch[m] < g + 1) lo = m + 1; else hi = m; }
        inv_cnt = 1.0f / fmaxf((float)(lo - s), 1.0f);
    }
    __syncthreads();
    for (int j = tid; j < 512; j += 256) {
        int l = j >> 7, c = j & 127;
        float a = coefL[l * 256 + c], d = coefL[l * 256 + 128 + c];
        z[j] = a * gsum[(size_t)l * NGRAPH * 128 + g * 128 + c] * inv_cnt + d;
    }
    if (tid < 64) z[512 + tid] = emb[g * 64 + tid];
    __syncthreads();
    {
        float acc = l1b[tid];
        for (int j = 0; j < 576; j++) acc += z[j] * l1w[j * 256 + tid];
        z1[tid] = fmaxf(acc, 0.f);
    }
    __syncthreads();
    if (tid < 128) {
        float acc = l2b[tid];
        for (int j = 0; j < 256; j++) acc += z1[j] * l2w[j * 128 + tid];
        z2[tid] = fmaxf(acc, 0.f);
    }
    __syncthreads();
    if (tid < 10) {
        float acc = l4b[tid];
        for (int j = 0; j < 128; j++) acc += z2[j] * l4w[j * 10 + tid];
        z3s[tid] = acc;
    }
    __syncthreads();
    if (tid == 0) {
        float m = z3s[0];
        for (int i = 1; i < 10; i++) m = fmaxf(m, z3s[i]);
        float se = 0.f;
        for (int i = 0; i < 10; i++) se += expf(z3s[i] - m);
        float lse = m + logf(se);
        for (int i = 0; i < 10; i++) out[g * 10 + i] = z3s[i] - lse;
    }
}

extern "C" void kernel_launch(void* const* d_in, const int* in_sizes, int n_in,
                              void* d_out, int out_size, void* d_ws, size_t ws_size,
                              hipStream_t stream) {
    (void)in_sizes; (void)n_in; (void)out_size; (void)ws_size;
    const float* x0   = (const float*)d_in[0];
    const int* ei     = (const int*)d_in[1];
    const int* src    = ei;
    const int* dst    = ei + N_EDGES;
    const int* batch  = (const int*)d_in[2];
    const float* emb  = (const float*)d_in[3];
    const float* eps  = (const float*)d_in[4];
    const float* W1   = (const float*)d_in[5];
    const float* b1   = (const float*)d_in[6];
    const float* W2   = (const float*)d_in[7];
    const float* b2   = (const float*)d_in[8];
    const float* gamma= (const float*)d_in[9];
    const float* beta = (const float*)d_in[10];
    const float* l1w  = (const float*)d_in[11];
    const float* l1b  = (const float*)d_in[12];
    const float* l2w  = (const float*)d_in[13];
    const float* l2b  = (const float*)d_in[14];
    const float* l4w  = (const float*)d_in[15];
    const float* l4b  = (const float*)d_in[16];

    char* ws = (char*)d_ws;
    size_t off = 0;
    auto alloc = [&](size_t bytes) -> char* {
        char* p = ws + off; off += (bytes + 255) & ~(size_t)255; return p;
    };
    int* deg    = (int*)alloc(N_NODES * 4);
    int* cursor = (int*)alloc(N_NODES * 4);
    size_t zero1_len = (char*)cursor - (char*)deg + (((size_t)N_NODES * 4 + 255) & ~(size_t)255);
    int* rowp   = (int*)alloc((N_NODES + 1) * 4);
    int* bscan  = (int*)alloc(N_NODES * 4);
    int* bsum   = (int*)alloc(SCAN_NB * 4);
    int* boff   = (int*)alloc(SCAN_NB * 4);
    int* col    = (int*)alloc(N_EDGES * 4);
    u32* xbf    = (u32*)alloc((size_t)N_NODES * 64 * 4);
    u32* agg    = (u32*)alloc((size_t)N_NODES * 64 * 4);
    u32* h2a    = (u32*)alloc((size_t)N_NODES * 64 * 4);
    u32* h2b    = (u32*)alloc((size_t)N_NODES * 64 * 4);
    short* W1t  = (short*)alloc((size_t)NLAYER * 128 * 128 * 2);
    short* W2t  = (short*)alloc((size_t)NLAYER * 128 * 128 * 2);
    float* partial = (float*)alloc((size_t)NBLK_MLP * 256 * 4);
    float* sumsL = (float*)alloc(NLAYER * 256 * 4);
    float* gsumL = (float*)alloc((size_t)NLAYER * NGRAPH * 128 * 4);
    size_t zero2_len = (char*)gsumL - (char*)sumsL + (size_t)NLAYER * NGRAPH * 128 * 4;
    float* coefL = (float*)alloc(NLAYER * 256 * 4);

    hipMemsetAsync(deg, 0, zero1_len, stream);
    hipMemsetAsync(sumsL, 0, zero2_len, stream);

    cvt_x<<<(N_NODES * 64 + 255) / 256, 256, 0, stream>>>((const float2*)x0, xbf);
    {
        dim3 gw(128, NLAYER, 2);
        cvt_w<<<gw, 128, 0, stream>>>(W1, W2, W1t, W2t);
    }
    count_deg<<<(N_EDGES + 255) / 256, 256, 0, stream>>>(dst, deg);
    scan_l1<<<SCAN_NB, 256, 0, stream>>>(deg, bscan, bsum);
    scan_l2<<<1, 256, 0, stream>>>(bsum, boff);
    scan_l3<<<SCAN_NB, 256, 0, stream>>>(bscan, boff, rowp);
    fill_csr<<<(N_EDGES + 255) / 256, 256, 0, stream>>>(src, dst, rowp, cursor, col);

    const u32* xin = xbf;
    for (int l = 0; l < NLAYER; ++l) {
        u32* h2 = (l & 1) ? h2b : h2a;
        const float* coef_prev = (l == 0) ? nullptr : (coefL + (l - 1) * 256);
        agg_kernel<<<(N_NODES + 3) / 4, 256, 0, stream>>>(
            xin, coef_prev, rowp, col, eps, l, agg);
        mlp_fused<<<NBLK_MLP, 256, 0, stream>>>(
            (const short*)agg, W1t + (size_t)l * 16384, b1 + l * 128,
            W2t + (size_t)l * 16384, b2 + l * 128, (short*)h2, batch,
            partial, gsumL + (size_t)l * NGRAPH * 128, N_NODES);
        reduce_partials<<<31, 256, 0, stream>>>(partial, sumsL + l * 256);
        bn_finalize<<<1, 128, 0, stream>>>(sumsL + l * 256, gamma, beta, l,
                                           coefL + l * 256);
        xin = h2;
    }
    head_kernel<<<NGRAPH, 256, 0, stream>>>(gsumL, coefL, batch, emb,
                                            l1w, l1b, l2w, l2b, l4w, l4b,
                                            (float*)d_out);
}